// Round 1
// baseline (348.924 us; speedup 1.0000x reference)
//
#include <hip/hip_runtime.h>
#include <hip/hip_bf16.h>
#include <cstdint>

#define DIMC 1024
#define HEADS 16
#define DHH 64
#define SEQ 4096
#define LATENT 1024
#define HISTC 3072
#define BATCH 2

typedef __attribute__((ext_vector_type(8))) __bf16 bf16x8;
typedef __attribute__((ext_vector_type(4))) float f32x4;

// ---------------- fp32 -> bf16 convert (vectorized) ----------------
__global__ void k_convert(const float* __restrict__ in, __bf16* __restrict__ out, int n) {
  int stride = gridDim.x * blockDim.x;
  int nc = n >> 2;
  for (int i = blockIdx.x * blockDim.x + threadIdx.x; i < nc; i += stride) {
    float4 v = reinterpret_cast<const float4*>(in)[i];
    union { __bf16 h[4]; uint64_t u; } p;
    p.h[0] = (__bf16)v.x; p.h[1] = (__bf16)v.y;
    p.h[2] = (__bf16)v.z; p.h[3] = (__bf16)v.w;
    reinterpret_cast<uint64_t*>(out)[i] = p.u;
  }
}

// ---------------- async global->LDS 16B ----------------
__device__ __forceinline__ void gload16(void* lds, const void* g) {
  __builtin_amdgcn_global_load_lds(
      (const __attribute__((address_space(1))) unsigned int*)g,
      (__attribute__((address_space(3))) unsigned int*)lds, 16, 0, 0);
}

// ---------------- GEMM: C[M,N] = A[M,K] @ Bw[N,K]^T (+bias) --------
// 128x128 tile, BK=32, 4 waves (2x2), each wave 64x64 via 4x4 16x16x32 mfma.
template<int QREMAP, int BIAS>
__launch_bounds__(256)
__global__ void k_gemm(const __bf16* __restrict__ A, const __bf16* __restrict__ Bw,
                       float* __restrict__ C, const float* __restrict__ bias,
                       int M, int N, int K) {
  __shared__ __align__(16) char lds[16384];
  const int t = threadIdx.x;
  const int l = t & 63, w = t >> 6;
  const int wr = w >> 1, wc = w & 1;
  const int m0 = blockIdx.y * 128, n0 = blockIdx.x * 128;
  const int lrow = l & 15, lk = l >> 4;
  f32x4 acc[4][4] = {};

  for (int k0 = 0; k0 < K; k0 += 32) {
    if (k0) __syncthreads();            // protect LDS from previous iter's reads
#pragma unroll
    for (int i = 0; i < 2; ++i) {
      int c = i * 256 + t;              // 0..511 : 16B chunk id
      int row = c >> 2, kc = c & 3;     // tile row, k-chunk
      int mi = m0 + row;
      if (QREMAP) mi += HISTC + (mi >> 10) * HISTC;   // q rows: b*4096+3072+i
      gload16(lds + c * 16, A + (size_t)mi * K + k0 + kc * 8);
      gload16(lds + 8192 + c * 16, Bw + (size_t)(n0 + row) * K + k0 + kc * 8);
    }
    __syncthreads();                    // vmcnt(0) drained by compiler before barrier
    bf16x8 af[4], bfr[4];
#pragma unroll
    for (int m = 0; m < 4; ++m)
      af[m] = *reinterpret_cast<const bf16x8*>(lds + (wr * 64 + m * 16 + lrow) * 64 + lk * 16);
#pragma unroll
    for (int n = 0; n < 4; ++n)
      bfr[n] = *reinterpret_cast<const bf16x8*>(lds + 8192 + (wc * 64 + n * 16 + lrow) * 64 + lk * 16);
#pragma unroll
    for (int m = 0; m < 4; ++m)
#pragma unroll
      for (int n = 0; n < 4; ++n)
        acc[m][n] = __builtin_amdgcn_mfma_f32_16x16x32_bf16(af[m], bfr[n], acc[m][n], 0, 0, 0);
  }

#pragma unroll
  for (int m = 0; m < 4; ++m)
#pragma unroll
    for (int n = 0; n < 4; ++n)
#pragma unroll
      for (int r = 0; r < 4; ++r) {
        int row = m0 + wr * 64 + m * 16 + (l >> 4) * 4 + r;   // D: row=(lane>>4)*4+reg
        int col = n0 + wc * 64 + n * 16 + (l & 15);           // D: col=lane&15
        float v = acc[m][n][r];
        if (BIAS) v += bias[col];
        C[(size_t)row * N + col] = v;
      }
}

// ---------------- kv epilogue: RoPE + per-head LN, write kvn + kvnT ----
__launch_bounds__(256)
__global__ void k_epi_kv(const float* __restrict__ kv_raw, __bf16* __restrict__ kvn,
                         __bf16* __restrict__ kvnT, const float* __restrict__ gamma,
                         const float* __restrict__ beta) {
  int bx = blockIdx.x;                  // 2048 = b(2) * h(16) * ntile(64)
  int nt = bx & 63, h = (bx >> 6) & 15, b = bx >> 10;
  int t = threadIdx.x, l = t & 63, w = t >> 6;
  int n0 = nt * 64;
  __shared__ __bf16 Tl[64][65];         // [d][n_local], padded
  float g = gamma[l], be = beta[l];
  float invf = expf(-(float)(l & 31) * 0.28782313662425574f);  // ln(10000)/32
  float sign = (l < 32) ? -1.f : 1.f;
#pragma unroll 1
  for (int ni = 0; ni < 16; ++ni) {
    int n = n0 + w * 16 + ni;
    float v = kv_raw[(size_t)(b * SEQ + n) * DIMC + h * DHH + l];
    float sv, cv;
    sincosf((float)n * invf, &sv, &cv);
    float partner = __shfl_xor(v, 32);
    float rope = v * cv + sign * partner * sv;
    float s = rope;
#pragma unroll
    for (int xm = 1; xm < 64; xm <<= 1) s += __shfl_xor(s, xm);
    float mu = s * (1.f / 64.f);
    float d = rope - mu;
    float vs = d * d;
#pragma unroll
    for (int xm = 1; xm < 64; xm <<= 1) vs += __shfl_xor(vs, xm);
    float inv = rsqrtf(vs * (1.f / 64.f) + 1e-5f);
    float y = d * inv * g + be;
    kvn[((size_t)(b * HEADS + h) * SEQ + n) * DHH + l] = (__bf16)y;
    Tl[l][w * 16 + ni] = (__bf16)y;
  }
  __syncthreads();
#pragma unroll 1
  for (int di = 0; di < 16; ++di) {
    int d = w * 16 + di;
    kvnT[((size_t)(b * HEADS + h) * DHH + d) * SEQ + n0 + l] = Tl[d][l];
  }
}

// ---------------- q epilogue: RoPE + scale ----------------
__launch_bounds__(256)
__global__ void k_epi_q(const float* __restrict__ q_raw, __bf16* __restrict__ qb) {
  int bx = blockIdx.x;                  // 512 = b(2)*h(16)*itile(16)
  int it = bx & 15, h = (bx >> 4) & 15, b = bx >> 8;
  int t = threadIdx.x, l = t & 63, w = t >> 6;
  int i0 = it * 64;
  float invf = expf(-(float)(l & 31) * 0.28782313662425574f);
  float sign = (l < 32) ? -1.f : 1.f;
#pragma unroll 1
  for (int ii = 0; ii < 16; ++ii) {
    int i = i0 + w * 16 + ii;
    float v = q_raw[(size_t)(b * LATENT + i) * DIMC + h * DHH + l];
    float sv, cv;
    sincosf((float)(HISTC + i) * invf, &sv, &cv);
    float partner = __shfl_xor(v, 32);
    float rope = (v * cv + sign * partner * sv) * 0.125f;   // * DH^-0.5
    qb[((size_t)(b * HEADS + h) * LATENT + i) * DHH + l] = (__bf16)rope;
  }
}

// ---------------- flash attention ----------------
// grid (itile=16, h=16, b=2), 4 waves x 16 q-rows. Online softmax fp32.
__launch_bounds__(256)
__global__ void k_flash(const __bf16* __restrict__ qb, const __bf16* __restrict__ kvn,
                        const __bf16* __restrict__ kvnT, __bf16* __restrict__ aout) {
  const int itile = blockIdx.x, h = blockIdx.y, b = blockIdx.z;
  const int t = threadIdx.x, l = t & 63, w = t >> 6;
  const int iw = itile * 64 + w * 16;
  const __bf16* qbase = qb + ((size_t)(b * HEADS + h) * LATENT + iw) * DHH;
  const __bf16* kbase = kvn + (size_t)(b * HEADS + h) * SEQ * DHH;
  const __bf16* vbase = kvnT + (size_t)(b * HEADS + h) * DHH * SEQ;
  const int lj = l & 15, lk = l >> 4;

  __shared__ __align__(16) __bf16 Pl[4][16][32];   // per-wave P tile

  bf16x8 qf[2];
#pragma unroll
  for (int kk = 0; kk < 2; ++kk)
    qf[kk] = *reinterpret_cast<const bf16x8*>(qbase + lj * DHH + kk * 32 + lk * 8);

  f32x4 acc[4] = {};
  float m_run[4], l_run[4];
#pragma unroll
  for (int r = 0; r < 4; ++r) { m_run[r] = -INFINITY; l_run[r] = 0.f; }

  const int jend = (SEQ < ((iw + 16 + HISTC + 31) & ~31)) ? SEQ : ((iw + 16 + HISTC + 31) & ~31);
  for (int j0 = 0; j0 < jend; j0 += 32) {
    f32x4 s0 = {}, s1 = {};
#pragma unroll
    for (int kk = 0; kk < 2; ++kk) {
      bf16x8 kf0 = *reinterpret_cast<const bf16x8*>(kbase + (size_t)(j0 + lj) * DHH + kk * 32 + lk * 8);
      bf16x8 kf1 = *reinterpret_cast<const bf16x8*>(kbase + (size_t)(j0 + 16 + lj) * DHH + kk * 32 + lk * 8);
      s0 = __builtin_amdgcn_mfma_f32_16x16x32_bf16(qf[kk], kf0, s0, 0, 0, 0);
      s1 = __builtin_amdgcn_mfma_f32_16x16x32_bf16(qf[kk], kf1, s1, 0, 0, 0);
    }
    if (j0 + 31 > iw + HISTC) {         // mask: j - HIST > i  ->  -1e30 (finite!)
#pragma unroll
      for (int r = 0; r < 4; ++r) {
        int i = iw + lk * 4 + r;
        if (j0 + lj > i + HISTC) s0[r] = -1e30f;
        if (j0 + 16 + lj > i + HISTC) s1[r] = -1e30f;
      }
    }
    float pm[4];
#pragma unroll
    for (int r = 0; r < 4; ++r) pm[r] = fmaxf(s0[r], s1[r]);
#pragma unroll
    for (int xm = 1; xm < 16; xm <<= 1)
#pragma unroll
      for (int r = 0; r < 4; ++r) pm[r] = fmaxf(pm[r], __shfl_xor(pm[r], xm));
    float sc[4];
#pragma unroll
    for (int r = 0; r < 4; ++r) {
      float mn = fmaxf(m_run[r], pm[r]);
      sc[r] = __expf(m_run[r] - mn);    // expf(-inf)=0 on first tile
      m_run[r] = mn;
      s0[r] = __expf(s0[r] - mn);
      s1[r] = __expf(s1[r] - mn);
    }
#pragma unroll
    for (int dt = 0; dt < 4; ++dt)
#pragma unroll
      for (int r = 0; r < 4; ++r) acc[dt][r] *= sc[r];
    float ps[4];
#pragma unroll
    for (int r = 0; r < 4; ++r) ps[r] = s0[r] + s1[r];
#pragma unroll
    for (int xm = 1; xm < 16; xm <<= 1)
#pragma unroll
      for (int r = 0; r < 4; ++r) ps[r] += __shfl_xor(ps[r], xm);
#pragma unroll
    for (int r = 0; r < 4; ++r) l_run[r] = l_run[r] * sc[r] + ps[r];
    // P (D-layout) -> LDS -> A-frag layout
#pragma unroll
    for (int r = 0; r < 4; ++r) {
      Pl[w][lk * 4 + r][lj] = (__bf16)s0[r];
      Pl[w][lk * 4 + r][16 + lj] = (__bf16)s1[r];
    }
    bf16x8 pf = *reinterpret_cast<const bf16x8*>(&Pl[w][lj][lk * 8]);
#pragma unroll
    for (int dt = 0; dt < 4; ++dt) {
      bf16x8 vf = *reinterpret_cast<const bf16x8*>(vbase + (size_t)(dt * 16 + lj) * SEQ + j0 + lk * 8);
      acc[dt] = __builtin_amdgcn_mfma_f32_16x16x32_bf16(pf, vf, acc[dt], 0, 0, 0);
    }
  }
#pragma unroll
  for (int dt = 0; dt < 4; ++dt)
#pragma unroll
    for (int r = 0; r < 4; ++r) {
      int i = iw + lk * 4 + r;
      float v = acc[dt][r] / l_run[r];
      aout[(size_t)(b * LATENT + i) * DIMC + h * DHH + dt * 16 + lj] = (__bf16)v;
    }
}

// ---------------- host launcher ----------------
extern "C" void kernel_launch(void* const* d_in, const int* in_sizes, int n_in,
                              void* d_out, int out_size, void* d_ws, size_t ws_size,
                              hipStream_t stream) {
  const float* x = (const float*)d_in[0];
  const float* Wq = (const float*)d_in[1];
  const float* Wkv = (const float*)d_in[2];
  const float* Wo = (const float*)d_in[3];
  const float* bo = (const float*)d_in[4];
  const float* gamma = (const float*)d_in[5];
  const float* beta = (const float*)d_in[6];

  char* ws = (char*)d_ws;
  size_t o = 0;
  __bf16* x16 = (__bf16*)(ws + o);  o += (size_t)BATCH * SEQ * DIMC * 2;
  __bf16* wq16 = (__bf16*)(ws + o); o += (size_t)DIMC * DIMC * 2;
  __bf16* wkv16 = (__bf16*)(ws + o); o += (size_t)DIMC * DIMC * 2;
  __bf16* wo16 = (__bf16*)(ws + o); o += (size_t)DIMC * DIMC * 2;
  float* kvraw = (float*)(ws + o);  o += (size_t)BATCH * SEQ * DIMC * 4;
  float* qraw = (float*)(ws + o);   o += (size_t)BATCH * LATENT * DIMC * 4;
  __bf16* kvn = (__bf16*)(ws + o);  o += (size_t)BATCH * HEADS * SEQ * DHH * 2;
  __bf16* kvnT = (__bf16*)(ws + o); o += (size_t)BATCH * HEADS * SEQ * DHH * 2;
  __bf16* qb = (__bf16*)(ws + o);   o += (size_t)BATCH * HEADS * LATENT * DHH * 2;
  __bf16* aout = (__bf16*)(ws + o); o += (size_t)BATCH * LATENT * DIMC * 2;

  k_convert<<<2048, 256, 0, stream>>>(x, x16, BATCH * SEQ * DIMC);
  k_convert<<<512, 256, 0, stream>>>(Wq, wq16, DIMC * DIMC);
  k_convert<<<512, 256, 0, stream>>>(Wkv, wkv16, DIMC * DIMC);
  k_convert<<<512, 256, 0, stream>>>(Wo, wo16, DIMC * DIMC);
  // kv = x @ Wkv^T  (M=8192)
  k_gemm<0, 0><<<dim3(8, 64), 256, 0, stream>>>(x16, wkv16, kvraw, nullptr, 8192, 1024, 1024);
  // q = x[:, HIST:, :] @ Wq^T  (M=2048, row-remapped)
  k_gemm<1, 0><<<dim3(8, 16), 256, 0, stream>>>(x16, wq16, qraw, nullptr, 2048, 1024, 1024);
  k_epi_kv<<<2048, 256, 0, stream>>>(kvraw, kvn, kvnT, gamma, beta);
  k_epi_q<<<512, 256, 0, stream>>>(qraw, qb);
  k_flash<<<dim3(16, 16, 2), 256, 0, stream>>>(qb, kvn, kvnT, aout);
  // out = attn_out @ Wo^T + bo
  k_gemm<0, 1><<<dim3(8, 16), 256, 0, stream>>>(aout, wo16, (float*)d_out, bo, 2048, 1024, 1024);
}

// Round 3
// 296.097 us; speedup vs baseline: 1.1784x; 1.1784x over previous
//
#include <hip/hip_runtime.h>
#include <hip/hip_bf16.h>
#include <cstdint>

#define DIMC 1024
#define HEADS 16
#define DHH 64
#define SEQ 4096
#define LATENT 1024
#define HISTC 3072
#define BATCH 2

typedef __attribute__((ext_vector_type(8))) __bf16 bf16x8;
typedef __attribute__((ext_vector_type(4))) float f32x4;
typedef __attribute__((ext_vector_type(16))) float f32x16;

// ---------------- fp32 -> bf16 convert (vectorized) ----------------
__global__ void k_convert(const float* __restrict__ in, __bf16* __restrict__ out, int n) {
  int stride = gridDim.x * blockDim.x;
  int nc = n >> 2;
  for (int i = blockIdx.x * blockDim.x + threadIdx.x; i < nc; i += stride) {
    float4 v = reinterpret_cast<const float4*>(in)[i];
    union { __bf16 h[4]; uint64_t u; } p;
    p.h[0] = (__bf16)v.x; p.h[1] = (__bf16)v.y;
    p.h[2] = (__bf16)v.z; p.h[3] = (__bf16)v.w;
    reinterpret_cast<uint64_t*>(out)[i] = p.u;
  }
}

// ---------------- async global->LDS 16B ----------------
__device__ __forceinline__ void gload16(void* lds, const void* g) {
  __builtin_amdgcn_global_load_lds(
      (const __attribute__((address_space(1))) unsigned int*)g,
      (__attribute__((address_space(3))) unsigned int*)lds, 16, 0, 0);
}

// ---------------- GEMM: C[M,N] = A[M,K] @ Bw[N,K]^T (+bias) --------
template<int QREMAP, int BIAS>
__launch_bounds__(256)
__global__ void k_gemm(const __bf16* __restrict__ A, const __bf16* __restrict__ Bw,
                       float* __restrict__ C, const float* __restrict__ bias,
                       int M, int N, int K) {
  __shared__ __align__(16) char lds[16384];
  const int t = threadIdx.x;
  const int l = t & 63, w = t >> 6;
  const int wr = w >> 1, wc = w & 1;
  const int m0 = blockIdx.y * 128, n0 = blockIdx.x * 128;
  const int lrow = l & 15, lk = l >> 4;
  f32x4 acc[4][4] = {};

  for (int k0 = 0; k0 < K; k0 += 32) {
    if (k0) __syncthreads();
#pragma unroll
    for (int i = 0; i < 2; ++i) {
      int c = i * 256 + t;
      int row = c >> 2, kc = c & 3;
      int mi = m0 + row;
      if (QREMAP) mi += HISTC + (mi >> 10) * HISTC;
      gload16(lds + c * 16, A + (size_t)mi * K + k0 + kc * 8);
      gload16(lds + 8192 + c * 16, Bw + (size_t)(n0 + row) * K + k0 + kc * 8);
    }
    __syncthreads();
    bf16x8 af[4], bfr[4];
#pragma unroll
    for (int m = 0; m < 4; ++m)
      af[m] = *reinterpret_cast<const bf16x8*>(lds + (wr * 64 + m * 16 + lrow) * 64 + lk * 16);
#pragma unroll
    for (int n = 0; n < 4; ++n)
      bfr[n] = *reinterpret_cast<const bf16x8*>(lds + 8192 + (wc * 64 + n * 16 + lrow) * 64 + lk * 16);
#pragma unroll
    for (int m = 0; m < 4; ++m)
#pragma unroll
      for (int n = 0; n < 4; ++n)
        acc[m][n] = __builtin_amdgcn_mfma_f32_16x16x32_bf16(af[m], bfr[n], acc[m][n], 0, 0, 0);
  }

#pragma unroll
  for (int m = 0; m < 4; ++m)
#pragma unroll
    for (int n = 0; n < 4; ++n)
#pragma unroll
      for (int r = 0; r < 4; ++r) {
        int row = m0 + wr * 64 + m * 16 + (l >> 4) * 4 + r;
        int col = n0 + wc * 64 + n * 16 + (l & 15);
        float v = acc[m][n][r];
        if (BIAS) v += bias[col];
        C[(size_t)row * N + col] = v;
      }
}

// ---------------- kv epilogue: RoPE + per-head LN, write kvn + kvnT ----
__launch_bounds__(256)
__global__ void k_epi_kv(const float* __restrict__ kv_raw, __bf16* __restrict__ kvn,
                         __bf16* __restrict__ kvnT, const float* __restrict__ gamma,
                         const float* __restrict__ beta) {
  int bx = blockIdx.x;
  int nt = bx & 63, h = (bx >> 6) & 15, b = bx >> 10;
  int t = threadIdx.x, l = t & 63, w = t >> 6;
  int n0 = nt * 64;
  __shared__ __bf16 Tl[64][65];
  float g = gamma[l], be = beta[l];
  float invf = expf(-(float)(l & 31) * 0.28782313662425574f);
  float sign = (l < 32) ? -1.f : 1.f;
#pragma unroll 1
  for (int ni = 0; ni < 16; ++ni) {
    int n = n0 + w * 16 + ni;
    float v = kv_raw[(size_t)(b * SEQ + n) * DIMC + h * DHH + l];
    float sv, cv;
    sincosf((float)n * invf, &sv, &cv);
    float partner = __shfl_xor(v, 32);
    float rope = v * cv + sign * partner * sv;
    float s = rope;
#pragma unroll
    for (int xm = 1; xm < 64; xm <<= 1) s += __shfl_xor(s, xm);
    float mu = s * (1.f / 64.f);
    float d = rope - mu;
    float vs = d * d;
#pragma unroll
    for (int xm = 1; xm < 64; xm <<= 1) vs += __shfl_xor(vs, xm);
    float inv = rsqrtf(vs * (1.f / 64.f) + 1e-5f);
    float y = d * inv * g + be;
    kvn[((size_t)(b * HEADS + h) * SEQ + n) * DHH + l] = (__bf16)y;
    Tl[l][w * 16 + ni] = (__bf16)y;
  }
  __syncthreads();
#pragma unroll 1
  for (int di = 0; di < 16; ++di) {
    int d = w * 16 + di;
    kvnT[((size_t)(b * HEADS + h) * DHH + d) * SEQ + n0 + l] = Tl[d][l];
  }
}

// ---------------- q epilogue: RoPE + scale (incl. log2e for base-2 softmax) ----
__launch_bounds__(256)
__global__ void k_epi_q(const float* __restrict__ q_raw, __bf16* __restrict__ qb) {
  int bx = blockIdx.x;
  int it = bx & 15, h = (bx >> 4) & 15, b = bx >> 8;
  int t = threadIdx.x, l = t & 63, w = t >> 6;
  int i0 = it * 64;
  float invf = expf(-(float)(l & 31) * 0.28782313662425574f);
  float sign = (l < 32) ? -1.f : 1.f;
#pragma unroll 1
  for (int ii = 0; ii < 16; ++ii) {
    int i = i0 + w * 16 + ii;
    float v = q_raw[(size_t)(b * LATENT + i) * DIMC + h * DHH + l];
    float sv, cv;
    sincosf((float)(HISTC + i) * invf, &sv, &cv);
    float partner = __shfl_xor(v, 32);
    // DH^-0.5 * log2(e) : softmax computed base-2
    float rope = (v * cv + sign * partner * sv) * 0.18033688011112042f;
    qb[((size_t)(b * HEADS + h) * LATENT + i) * DHH + l] = (__bf16)rope;
  }
}

// ---------------- helpers for flash ----------------
__device__ __forceinline__ float fexp2(float x) {
#if __has_builtin(__builtin_amdgcn_exp2f)
  return __builtin_amdgcn_exp2f(x);
#else
  return exp2f(x);
#endif
}

__device__ __forceinline__ unsigned pk2(float a, float b) {
  union { __bf16 h[2]; unsigned u; } x;
  x.h[0] = (__bf16)a; x.h[1] = (__bf16)b;
  return x.u;
}

// ---------------- flash attention v2 ----------------
// grid (32, H, B): block = 32 q-rows, 4 waves split the j-range (flash split-K),
// merged once via LDS. Swapped QK^T on 32x32x16 mfma: lane owns q-row = lane&31,
// scores lane-local (16 regs + lane^32 partner). No LDS in main loop.
__launch_bounds__(256)
__global__ void k_flash2(const __bf16* __restrict__ qb, const __bf16* __restrict__ kvn,
                         const __bf16* __restrict__ kvnT, __bf16* __restrict__ aout) {
  const int itile = blockIdx.x, h = blockIdx.y, b = blockIdx.z;
  const int t = threadIdx.x, l = t & 63, w = t >> 6;
  const int q = l & 31, hi = l >> 5;
  const int iw = itile * 32;
  const int i = iw + q;
  const __bf16* qbase = qb + ((size_t)(b * HEADS + h) * LATENT + iw) * DHH;
  const __bf16* kbase = kvn + (size_t)(b * HEADS + h) * SEQ * DHH;
  const __bf16* vbase = kvnT + (size_t)(b * HEADS + h) * DHH * SEQ;

  __shared__ float Olds[4][32][65];
  __shared__ float Mlds[4][32];
  __shared__ float Llds[4][32];

  // Q as B-operand: col=lane&31=q-row, k=(lane>>5)*8+e
  bf16x8 qf[4];
#pragma unroll
  for (int c = 0; c < 4; ++c)
    qf[c] = *reinterpret_cast<const bf16x8*>(qbase + (size_t)q * DHH + c * 16 + hi * 8);

  f32x16 O0 = {}, O1 = {};
  float m_run = -INFINITY, l_run = 0.f;

  const int nt = itile + 97;               // tiles of 32 keys: (iw+32+HISTC)/32
  const int t0 = (nt * w) >> 2, t1 = (nt * (w + 1)) >> 2;

  for (int tt = t0; tt < t1; ++tt) {
    const int j0 = tt * 32;
    // QK^T swapped: S[key][qrow]
    f32x16 S = {};
#pragma unroll
    for (int c = 0; c < 4; ++c) {
      bf16x8 kf = *reinterpret_cast<const bf16x8*>(kbase + (size_t)(j0 + q) * DHH + c * 16 + hi * 8);
      S = __builtin_amdgcn_mfma_f32_32x32x16_bf16(kf, qf[c], S, 0, 0, 0);
    }
    if (j0 + 31 > iw + HISTC) {            // causal-ish mask: j - HIST > i
#pragma unroll
      for (int r = 0; r < 16; ++r) {
        int j = j0 + (r & 3) + 8 * (r >> 2) + 4 * hi;
        if (j > i + HISTC) S[r] = -1e30f;
      }
    }
    // row max: in-lane tree over 16 + one partner exchange
    float a8[8];
#pragma unroll
    for (int r = 0; r < 8; ++r) a8[r] = fmaxf(S[r], S[r + 8]);
    float a4_0 = fmaxf(a8[0], a8[4]), a4_1 = fmaxf(a8[1], a8[5]);
    float a4_2 = fmaxf(a8[2], a8[6]), a4_3 = fmaxf(a8[3], a8[7]);
    float pm = fmaxf(fmaxf(a4_0, a4_1), fmaxf(a4_2, a4_3));
    pm = fmaxf(pm, __shfl_xor(pm, 32));
    // defer-max (T13): rescale only if some row's max grew past threshold (log2 units; P <= 2^8)
    if (__any(pm > m_run + 8.0f)) {
      float mn = fmaxf(m_run, pm);
      float sc = fexp2(m_run - mn);        // first tile: exp2(-inf)=0
      m_run = mn;
      l_run *= sc;
#pragma unroll
      for (int r = 0; r < 16; ++r) { O0[r] *= sc; O1[r] *= sc; }
    }
    // P = 2^(S - m), row sum
    float p[16];
#pragma unroll
    for (int r = 0; r < 16; ++r) p[r] = fexp2(S[r] - m_run);
    float s8[8];
#pragma unroll
    for (int r = 0; r < 8; ++r) s8[r] = p[r] + p[r + 8];
    float s4_0 = s8[0] + s8[4], s4_1 = s8[1] + s8[5];
    float s4_2 = s8[2] + s8[6], s4_3 = s8[3] + s8[7];
    float ssum = (s4_0 + s4_1) + (s4_2 + s4_3);
    l_run += ssum + __shfl_xor(ssum, 32);
    // pack P -> bf16 pairs. Lane (q,hi) holds P[key][q] for keys
    // j0 + {r&3 + 8*(r>>2) + 4*hi}. PV B-frag needs keys j0 + half*16 + hi*8 + e.
    // Assemble via explicit partner exchange (shfl_xor 32) — unambiguous semantics.
    unsigned qw0 = pk2(p[0], p[1]),  qw1 = pk2(p[2], p[3]);
    unsigned qw2 = pk2(p[4], p[5]),  qw3 = pk2(p[6], p[7]);
    unsigned qw4 = pk2(p[8], p[9]),  qw5 = pk2(p[10], p[11]);
    unsigned qw6 = pk2(p[12], p[13]), qw7 = pk2(p[14], p[15]);
    unsigned rw0 = __shfl_xor(qw0, 32), rw1 = __shfl_xor(qw1, 32);
    unsigned rw2 = __shfl_xor(qw2, 32), rw3 = __shfl_xor(qw3, 32);
    unsigned rw4 = __shfl_xor(qw4, 32), rw5 = __shfl_xor(qw5, 32);
    unsigned rw6 = __shfl_xor(qw6, 32), rw7 = __shfl_xor(qw7, 32);
    union { unsigned u[4]; bf16x8 v; } pf0, pf1;
    // frag0 (keys j0+0..15): hi=0 wants keys 0-7 = [own(0,1),(2,3), partner(4,5),(6,7)]
    //                         hi=1 wants keys 8-15 = [partner(8,9),(10,11), own(12,13),(14,15)]
    pf0.u[0] = hi ? rw2 : qw0;
    pf0.u[1] = hi ? rw3 : qw1;
    pf0.u[2] = hi ? qw2 : rw0;
    pf0.u[3] = hi ? qw3 : rw1;
    // frag1 (keys j0+16..31)
    pf1.u[0] = hi ? rw6 : qw4;
    pf1.u[1] = hi ? rw7 : qw5;
    pf1.u[2] = hi ? qw6 : rw4;
    pf1.u[3] = hi ? qw7 : rw5;
    // PV: O[d][q] += V^T-chunk x P, d-blocks of 32, j-halves of 16
    {
      const __bf16* vb0 = vbase + (size_t)q * SEQ + j0 + hi * 8;
      const __bf16* vb1 = vbase + (size_t)(32 + q) * SEQ + j0 + hi * 8;
      bf16x8 va00 = *reinterpret_cast<const bf16x8*>(vb0);
      bf16x8 va01 = *reinterpret_cast<const bf16x8*>(vb0 + 16);
      bf16x8 va10 = *reinterpret_cast<const bf16x8*>(vb1);
      bf16x8 va11 = *reinterpret_cast<const bf16x8*>(vb1 + 16);
      O0 = __builtin_amdgcn_mfma_f32_32x32x16_bf16(va00, pf0.v, O0, 0, 0, 0);
      O0 = __builtin_amdgcn_mfma_f32_32x32x16_bf16(va01, pf1.v, O0, 0, 0, 0);
      O1 = __builtin_amdgcn_mfma_f32_32x32x16_bf16(va10, pf0.v, O1, 0, 0, 0);
      O1 = __builtin_amdgcn_mfma_f32_32x32x16_bf16(va11, pf1.v, O1, 0, 0, 0);
    }
  }

  // -------- merge the 4 waves' partial (O, m, l) --------
  if (hi == 0) { Mlds[w][q] = m_run; Llds[w][q] = l_run; }
#pragma unroll
  for (int r = 0; r < 16; ++r) {
    int d = (r & 3) + 8 * (r >> 2) + 4 * hi;
    Olds[w][q][d] = O0[r];
    Olds[w][q][32 + d] = O1[r];
  }
  __syncthreads();
  {
    int mi = t >> 3, d0 = (t & 7) * 8;
    float m0v = Mlds[0][mi], m1v = Mlds[1][mi], m2v = Mlds[2][mi], m3v = Mlds[3][mi];
    float mm = fmaxf(fmaxf(m0v, m1v), fmaxf(m2v, m3v));
    float sc0 = fexp2(m0v - mm), sc1 = fexp2(m1v - mm);
    float sc2 = fexp2(m2v - mm), sc3 = fexp2(m3v - mm);
    float ll = Llds[0][mi] * sc0 + Llds[1][mi] * sc1 + Llds[2][mi] * sc2 + Llds[3][mi] * sc3;
    float inv = 1.f / ll;
    union { __bf16 hh[8]; uint4 u4; } pk;
#pragma unroll
    for (int e = 0; e < 8; ++e) {
      float o = Olds[0][mi][d0 + e] * sc0 + Olds[1][mi][d0 + e] * sc1 +
                Olds[2][mi][d0 + e] * sc2 + Olds[3][mi][d0 + e] * sc3;
      pk.hh[e] = (__bf16)(o * inv);
    }
    *reinterpret_cast<uint4*>(aout + ((size_t)(b * LATENT) + iw + mi) * DIMC + h * DHH + d0) = pk.u4;
  }
}

// ---------------- host launcher ----------------
extern "C" void kernel_launch(void* const* d_in, const int* in_sizes, int n_in,
                              void* d_out, int out_size, void* d_ws, size_t ws_size,
                              hipStream_t stream) {
  const float* x = (const float*)d_in[0];
  const float* Wq = (const float*)d_in[1];
  const float* Wkv = (const float*)d_in[2];
  const float* Wo = (const float*)d_in[3];
  const float* bo = (const float*)d_in[4];
  const float* gamma = (const float*)d_in[5];
  const float* beta = (const float*)d_in[6];

  char* ws = (char*)d_ws;
  size_t o = 0;
  __bf16* x16 = (__bf16*)(ws + o);  o += (size_t)BATCH * SEQ * DIMC * 2;
  __bf16* wq16 = (__bf16*)(ws + o); o += (size_t)DIMC * DIMC * 2;
  __bf16* wkv16 = (__bf16*)(ws + o); o += (size_t)DIMC * DIMC * 2;
  __bf16* wo16 = (__bf16*)(ws + o); o += (size_t)DIMC * DIMC * 2;
  float* kvraw = (float*)(ws + o);  o += (size_t)BATCH * SEQ * DIMC * 4;
  float* qraw = (float*)(ws + o);   o += (size_t)BATCH * LATENT * DIMC * 4;
  __bf16* kvn = (__bf16*)(ws + o);  o += (size_t)BATCH * HEADS * SEQ * DHH * 2;
  __bf16* kvnT = (__bf16*)(ws + o); o += (size_t)BATCH * HEADS * SEQ * DHH * 2;
  __bf16* qb = (__bf16*)(ws + o);   o += (size_t)BATCH * HEADS * LATENT * DHH * 2;
  __bf16* aout = (__bf16*)(ws + o); o += (size_t)BATCH * LATENT * DIMC * 2;

  k_convert<<<2048, 256, 0, stream>>>(x, x16, BATCH * SEQ * DIMC);
  k_convert<<<512, 256, 0, stream>>>(Wq, wq16, DIMC * DIMC);
  k_convert<<<512, 256, 0, stream>>>(Wkv, wkv16, DIMC * DIMC);
  k_convert<<<512, 256, 0, stream>>>(Wo, wo16, DIMC * DIMC);
  k_gemm<0, 0><<<dim3(8, 64), 256, 0, stream>>>(x16, wkv16, kvraw, nullptr, 8192, 1024, 1024);
  k_gemm<1, 0><<<dim3(8, 16), 256, 0, stream>>>(x16, wq16, qraw, nullptr, 2048, 1024, 1024);
  k_epi_kv<<<2048, 256, 0, stream>>>(kvraw, kvn, kvnT, gamma, beta);
  k_epi_q<<<512, 256, 0, stream>>>(qraw, qb);
  k_flash2<<<dim3(32, 16, 2), 256, 0, stream>>>(qb, kvn, kvnT, aout);
  k_gemm<0, 1><<<dim3(8, 16), 256, 0, stream>>>(aout, wo16, (float*)d_out, bo, 2048, 1024, 1024);
}

// Round 4
// 225.878 us; speedup vs baseline: 1.5447x; 1.3109x over previous
//
#include <hip/hip_runtime.h>
#include <hip/hip_bf16.h>
#include <cstdint>

#define DIMC 1024
#define HEADS 16
#define DHH 64
#define SEQ 4096
#define LATENT 1024
#define HISTC 3072
#define BATCH 2

typedef __attribute__((ext_vector_type(8))) __bf16 bf16x8;
typedef __attribute__((ext_vector_type(4))) float f32x4;
typedef __attribute__((ext_vector_type(16))) float f32x16;

// ---------------- fp32 -> bf16 convert (vectorized) ----------------
__global__ void k_convert(const float* __restrict__ in, __bf16* __restrict__ out, int n) {
  int stride = gridDim.x * blockDim.x;
  int nc = n >> 2;
  for (int i = blockIdx.x * blockDim.x + threadIdx.x; i < nc; i += stride) {
    float4 v = reinterpret_cast<const float4*>(in)[i];
    union { __bf16 h[4]; uint64_t u; } p;
    p.h[0] = (__bf16)v.x; p.h[1] = (__bf16)v.y;
    p.h[2] = (__bf16)v.z; p.h[3] = (__bf16)v.w;
    reinterpret_cast<uint64_t*>(out)[i] = p.u;
  }
}

// ---------------- async global->LDS 16B ----------------
__device__ __forceinline__ void gload16(void* lds, const void* g) {
  __builtin_amdgcn_global_load_lds(
      (const __attribute__((address_space(1))) unsigned int*)g,
      (__attribute__((address_space(3))) unsigned int*)lds, 16, 0, 0);
}

// ---------------- GEMM: C[M,N] = A[M,K] @ Bw[N,K]^T (+bias) --------
template<int QREMAP, int BIAS>
__launch_bounds__(256)
__global__ void k_gemm(const __bf16* __restrict__ A, const __bf16* __restrict__ Bw,
                       float* __restrict__ C, const float* __restrict__ bias,
                       int M, int N, int K) {
  __shared__ __align__(16) char lds[16384];
  const int t = threadIdx.x;
  const int l = t & 63, w = t >> 6;
  const int wr = w >> 1, wc = w & 1;
  const int m0 = blockIdx.y * 128, n0 = blockIdx.x * 128;
  const int lrow = l & 15, lk = l >> 4;
  f32x4 acc[4][4] = {};

  for (int k0 = 0; k0 < K; k0 += 32) {
    if (k0) __syncthreads();
#pragma unroll
    for (int i = 0; i < 2; ++i) {
      int c = i * 256 + t;
      int row = c >> 2, kc = c & 3;
      int mi = m0 + row;
      if (QREMAP) mi += HISTC + (mi >> 10) * HISTC;
      gload16(lds + c * 16, A + (size_t)mi * K + k0 + kc * 8);
      gload16(lds + 8192 + c * 16, Bw + (size_t)(n0 + row) * K + k0 + kc * 8);
    }
    __syncthreads();
    bf16x8 af[4], bfr[4];
#pragma unroll
    for (int m = 0; m < 4; ++m)
      af[m] = *reinterpret_cast<const bf16x8*>(lds + (wr * 64 + m * 16 + lrow) * 64 + lk * 16);
#pragma unroll
    for (int n = 0; n < 4; ++n)
      bfr[n] = *reinterpret_cast<const bf16x8*>(lds + 8192 + (wc * 64 + n * 16 + lrow) * 64 + lk * 16);
#pragma unroll
    for (int m = 0; m < 4; ++m)
#pragma unroll
      for (int n = 0; n < 4; ++n)
        acc[m][n] = __builtin_amdgcn_mfma_f32_16x16x32_bf16(af[m], bfr[n], acc[m][n], 0, 0, 0);
  }

#pragma unroll
  for (int m = 0; m < 4; ++m)
#pragma unroll
    for (int n = 0; n < 4; ++n)
#pragma unroll
      for (int r = 0; r < 4; ++r) {
        int row = m0 + wr * 64 + m * 16 + (l >> 4) * 4 + r;
        int col = n0 + wc * 64 + n * 16 + (l & 15);
        float v = acc[m][n][r];
        if (BIAS) v += bias[col];
        C[(size_t)row * N + col] = v;
      }
}

// ---------------- kv epilogue: RoPE + per-head LN, write kvn + kvnT ----
__launch_bounds__(256)
__global__ void k_epi_kv(const float* __restrict__ kv_raw, __bf16* __restrict__ kvn,
                         __bf16* __restrict__ kvnT, const float* __restrict__ gamma,
                         const float* __restrict__ beta) {
  int bx = blockIdx.x;
  int nt = bx & 63, h = (bx >> 6) & 15, b = bx >> 10;
  int t = threadIdx.x, l = t & 63, w = t >> 6;
  int n0 = nt * 64;
  __shared__ __bf16 Tl[64][65];
  float g = gamma[l], be = beta[l];
  float invf = expf(-(float)(l & 31) * 0.28782313662425574f);
  float sign = (l < 32) ? -1.f : 1.f;
#pragma unroll 1
  for (int ni = 0; ni < 16; ++ni) {
    int n = n0 + w * 16 + ni;
    float v = kv_raw[(size_t)(b * SEQ + n) * DIMC + h * DHH + l];
    float sv, cv;
    sincosf((float)n * invf, &sv, &cv);
    float partner = __shfl_xor(v, 32);
    float rope = v * cv + sign * partner * sv;
    float s = rope;
#pragma unroll
    for (int xm = 1; xm < 64; xm <<= 1) s += __shfl_xor(s, xm);
    float mu = s * (1.f / 64.f);
    float d = rope - mu;
    float vs = d * d;
#pragma unroll
    for (int xm = 1; xm < 64; xm <<= 1) vs += __shfl_xor(vs, xm);
    float inv = rsqrtf(vs * (1.f / 64.f) + 1e-5f);
    float y = d * inv * g + be;
    kvn[((size_t)(b * HEADS + h) * SEQ + n) * DHH + l] = (__bf16)y;
    Tl[l][w * 16 + ni] = (__bf16)y;
  }
  __syncthreads();
#pragma unroll 1
  for (int di = 0; di < 16; ++di) {
    int d = w * 16 + di;
    kvnT[((size_t)(b * HEADS + h) * DHH + d) * SEQ + n0 + l] = Tl[d][l];
  }
}

// ---------------- q epilogue: RoPE + scale (incl. log2e for base-2 softmax) ----
__launch_bounds__(256)
__global__ void k_epi_q(const float* __restrict__ q_raw, __bf16* __restrict__ qb) {
  int bx = blockIdx.x;
  int it = bx & 15, h = (bx >> 4) & 15, b = bx >> 8;
  int t = threadIdx.x, l = t & 63, w = t >> 6;
  int i0 = it * 64;
  float invf = expf(-(float)(l & 31) * 0.28782313662425574f);
  float sign = (l < 32) ? -1.f : 1.f;
#pragma unroll 1
  for (int ii = 0; ii < 16; ++ii) {
    int i = i0 + w * 16 + ii;
    float v = q_raw[(size_t)(b * LATENT + i) * DIMC + h * DHH + l];
    float sv, cv;
    sincosf((float)(HISTC + i) * invf, &sv, &cv);
    float partner = __shfl_xor(v, 32);
    // DH^-0.5 * log2(e) : softmax computed base-2
    float rope = (v * cv + sign * partner * sv) * 0.18033688011112042f;
    qb[((size_t)(b * HEADS + h) * LATENT + i) * DHH + l] = (__bf16)rope;
  }
}

// ---------------- helpers for flash ----------------
__device__ __forceinline__ float fexp2(float x) {
#if __has_builtin(__builtin_amdgcn_exp2f)
  return __builtin_amdgcn_exp2f(x);
#else
  return exp2f(x);
#endif
}

__device__ __forceinline__ unsigned pk2(float a, float b) {
  union { __bf16 h[2]; unsigned u; } x;
  x.h[0] = (__bf16)a; x.h[1] = (__bf16)b;
  return x.u;
}

// ---------------- flash attention v3 ----------------
// 1D grid 1024, XCD-aware decomposition: xcd = bid&7, 4 (b,h) groups per XCD,
// 32 itiles per group -> each XCD's L2 holds exactly its 4 heads' K/V (4 MB).
// Per block: 32 q-rows, 4 waves split the j-range, merged via LDS (chunked).
// V staged per-wave into LDS with coalesced loads, software-pipelined 1 tile ahead.
__launch_bounds__(256)
__global__ void k_flash3(const __bf16* __restrict__ qb, const __bf16* __restrict__ kvn,
                         const __bf16* __restrict__ kvnT, __bf16* __restrict__ aout) {
  const int bid = blockIdx.x;
  const int bh = (bid & 7) + 8 * (bid >> 8);      // group -> same XCD for all 32 itiles
  const int itile = (bid >> 3) & 31;
  const int h = bh & 15, b = bh >> 4;
  const int t = threadIdx.x, l = t & 63, w = t >> 6;
  const int q = l & 31, hi = l >> 5;
  const int iw = itile * 32;
  const int i = iw + q;
  const __bf16* qbase = qb + ((size_t)(b * HEADS + h) * LATENT + iw) * DHH;
  const __bf16* kbase = kvn + (size_t)(b * HEADS + h) * SEQ * DHH;
  const __bf16* vbase = kvnT + (size_t)(b * HEADS + h) * DHH * SEQ;

  __shared__ float Olds[4][32][33];               // chunked merge buffer (32 d at a time)
  __shared__ float Mlds[4][32];
  __shared__ float Llds[4][32];
  __shared__ __align__(16) __bf16 Vlds[4][64][40]; // per-wave V tile, 80B rows (padded)

  // Q as B-operand: col=lane&31=q-row, k=(lane>>5)*8+e
  bf16x8 qf[4];
#pragma unroll
  for (int c = 0; c < 4; ++c)
    qf[c] = *reinterpret_cast<const bf16x8*>(qbase + (size_t)q * DHH + c * 16 + hi * 8);

  f32x16 O0 = {}, O1 = {};
  float m_run = -INFINITY, l_run = 0.f;

  const int nt = itile + 97;               // tiles of 32 keys
  const int t0 = (nt * w) >> 2, t1 = (nt * (w + 1)) >> 2;

  // V staging: lane covers row (i*16 + l>>2), key-chunk (l&3)*8 of the 32-key tile.
  const int srow = l >> 2, scol = l & 3;
  bf16x8 vreg[4];
#pragma unroll
  for (int ii = 0; ii < 4; ++ii)
    vreg[ii] = *reinterpret_cast<const bf16x8*>(
        vbase + (size_t)(ii * 16 + srow) * SEQ + t0 * 32 + scol * 8);

  for (int tt = t0; tt < t1; ++tt) {
    const int j0 = tt * 32;
    // commit V(tt) to this wave's LDS region (wave-private: no barrier needed)
#pragma unroll
    for (int ii = 0; ii < 4; ++ii)
      *reinterpret_cast<bf16x8*>(&Vlds[w][ii * 16 + srow][scol * 8]) = vreg[ii];
    // prefetch V(tt+1)
    if (tt + 1 < t1) {
#pragma unroll
      for (int ii = 0; ii < 4; ++ii)
        vreg[ii] = *reinterpret_cast<const bf16x8*>(
            vbase + (size_t)(ii * 16 + srow) * SEQ + (tt + 1) * 32 + scol * 8);
    }
    // QK^T swapped: S[key][qrow]
    f32x16 S = {};
#pragma unroll
    for (int c = 0; c < 4; ++c) {
      bf16x8 kf = *reinterpret_cast<const bf16x8*>(kbase + (size_t)(j0 + q) * DHH + c * 16 + hi * 8);
      S = __builtin_amdgcn_mfma_f32_32x32x16_bf16(kf, qf[c], S, 0, 0, 0);
    }
    if (j0 + 31 > iw + HISTC) {            // mask: j - HIST > i
#pragma unroll
      for (int r = 0; r < 16; ++r) {
        int j = j0 + (r & 3) + 8 * (r >> 2) + 4 * hi;
        if (j > i + HISTC) S[r] = -1e30f;
      }
    }
    // row max: in-lane tree + one partner exchange
    float a8[8];
#pragma unroll
    for (int r = 0; r < 8; ++r) a8[r] = fmaxf(S[r], S[r + 8]);
    float a4_0 = fmaxf(a8[0], a8[4]), a4_1 = fmaxf(a8[1], a8[5]);
    float a4_2 = fmaxf(a8[2], a8[6]), a4_3 = fmaxf(a8[3], a8[7]);
    float pm = fmaxf(fmaxf(a4_0, a4_1), fmaxf(a4_2, a4_3));
    pm = fmaxf(pm, __shfl_xor(pm, 32));
    // defer-max (T13), log2 units; P <= 2^8
    if (__any(pm > m_run + 8.0f)) {
      float mn = fmaxf(m_run, pm);
      float sc = fexp2(m_run - mn);        // first tile: exp2(-inf)=0
      m_run = mn;
      l_run *= sc;
#pragma unroll
      for (int r = 0; r < 16; ++r) { O0[r] *= sc; O1[r] *= sc; }
    }
    // P = 2^(S - m), row sum
    float p[16];
#pragma unroll
    for (int r = 0; r < 16; ++r) p[r] = fexp2(S[r] - m_run);
    float s8[8];
#pragma unroll
    for (int r = 0; r < 8; ++r) s8[r] = p[r] + p[r + 8];
    float s4_0 = s8[0] + s8[4], s4_1 = s8[1] + s8[5];
    float s4_2 = s8[2] + s8[6], s4_3 = s8[3] + s8[7];
    float ssum = (s4_0 + s4_1) + (s4_2 + s4_3);
    l_run += ssum + __shfl_xor(ssum, 32);
    // pack P -> bf16, exchange into PV B-frag layout (verified round-3 mapping)
    unsigned qw0 = pk2(p[0], p[1]),  qw1 = pk2(p[2], p[3]);
    unsigned qw2 = pk2(p[4], p[5]),  qw3 = pk2(p[6], p[7]);
    unsigned qw4 = pk2(p[8], p[9]),  qw5 = pk2(p[10], p[11]);
    unsigned qw6 = pk2(p[12], p[13]), qw7 = pk2(p[14], p[15]);
    unsigned rw0 = __shfl_xor(qw0, 32), rw1 = __shfl_xor(qw1, 32);
    unsigned rw2 = __shfl_xor(qw2, 32), rw3 = __shfl_xor(qw3, 32);
    unsigned rw4 = __shfl_xor(qw4, 32), rw5 = __shfl_xor(qw5, 32);
    unsigned rw6 = __shfl_xor(qw6, 32), rw7 = __shfl_xor(qw7, 32);
    union { unsigned u[4]; bf16x8 v; } pf0, pf1;
    pf0.u[0] = hi ? rw2 : qw0;
    pf0.u[1] = hi ? rw3 : qw1;
    pf0.u[2] = hi ? qw2 : rw0;
    pf0.u[3] = hi ? qw3 : rw1;
    pf1.u[0] = hi ? rw6 : qw4;
    pf1.u[1] = hi ? rw7 : qw5;
    pf1.u[2] = hi ? qw6 : rw4;
    pf1.u[3] = hi ? qw7 : rw5;
    // PV: V^T frags from this wave's LDS tile
    {
      bf16x8 va00 = *reinterpret_cast<const bf16x8*>(&Vlds[w][q][hi * 8]);
      bf16x8 va01 = *reinterpret_cast<const bf16x8*>(&Vlds[w][q][16 + hi * 8]);
      bf16x8 va10 = *reinterpret_cast<const bf16x8*>(&Vlds[w][32 + q][hi * 8]);
      bf16x8 va11 = *reinterpret_cast<const bf16x8*>(&Vlds[w][32 + q][16 + hi * 8]);
      O0 = __builtin_amdgcn_mfma_f32_32x32x16_bf16(va00, pf0.v, O0, 0, 0, 0);
      O0 = __builtin_amdgcn_mfma_f32_32x32x16_bf16(va01, pf1.v, O0, 0, 0, 0);
      O1 = __builtin_amdgcn_mfma_f32_32x32x16_bf16(va10, pf0.v, O1, 0, 0, 0);
      O1 = __builtin_amdgcn_mfma_f32_32x32x16_bf16(va11, pf1.v, O1, 0, 0, 0);
    }
  }

  // -------- merge the 4 waves' partial (O, m, l), chunked over d --------
  if (hi == 0) { Mlds[w][q] = m_run; Llds[w][q] = l_run; }
#pragma unroll
  for (int r = 0; r < 16; ++r)
    Olds[w][q][(r & 3) + 8 * (r >> 2) + 4 * hi] = O0[r];
  __syncthreads();
  const int mi = t >> 3, dl = (t & 7) * 4;
  float m0v = Mlds[0][mi], m1v = Mlds[1][mi], m2v = Mlds[2][mi], m3v = Mlds[3][mi];
  float mm = fmaxf(fmaxf(m0v, m1v), fmaxf(m2v, m3v));
  float sc0 = fexp2(m0v - mm), sc1 = fexp2(m1v - mm);
  float sc2 = fexp2(m2v - mm), sc3 = fexp2(m3v - mm);
  float ll = Llds[0][mi] * sc0 + Llds[1][mi] * sc1 + Llds[2][mi] * sc2 + Llds[3][mi] * sc3;
  float inv = 1.f / ll;
  __bf16* orow = aout + ((size_t)(b * LATENT) + iw + mi) * DIMC + h * DHH;
  {
    union { __bf16 hh[4]; uint2 u2; } pkv;
#pragma unroll
    for (int e = 0; e < 4; ++e) {
      float o = Olds[0][mi][dl + e] * sc0 + Olds[1][mi][dl + e] * sc1 +
                Olds[2][mi][dl + e] * sc2 + Olds[3][mi][dl + e] * sc3;
      pkv.hh[e] = (__bf16)(o * inv);
    }
    *reinterpret_cast<uint2*>(orow + dl) = pkv.u2;
  }
  __syncthreads();
#pragma unroll
  for (int r = 0; r < 16; ++r)
    Olds[w][q][(r & 3) + 8 * (r >> 2) + 4 * hi] = O1[r];
  __syncthreads();
  {
    union { __bf16 hh[4]; uint2 u2; } pkv;
#pragma unroll
    for (int e = 0; e < 4; ++e) {
      float o = Olds[0][mi][dl + e] * sc0 + Olds[1][mi][dl + e] * sc1 +
                Olds[2][mi][dl + e] * sc2 + Olds[3][mi][dl + e] * sc3;
      pkv.hh[e] = (__bf16)(o * inv);
    }
    *reinterpret_cast<uint2*>(orow + 32 + dl) = pkv.u2;
  }
}

// ---------------- host launcher ----------------
extern "C" void kernel_launch(void* const* d_in, const int* in_sizes, int n_in,
                              void* d_out, int out_size, void* d_ws, size_t ws_size,
                              hipStream_t stream) {
  const float* x = (const float*)d_in[0];
  const float* Wq = (const float*)d_in[1];
  const float* Wkv = (const float*)d_in[2];
  const float* Wo = (const float*)d_in[3];
  const float* bo = (const float*)d_in[4];
  const float* gamma = (const float*)d_in[5];
  const float* beta = (const float*)d_in[6];

  char* ws = (char*)d_ws;
  size_t o = 0;
  __bf16* x16 = (__bf16*)(ws + o);  o += (size_t)BATCH * SEQ * DIMC * 2;
  __bf16* wq16 = (__bf16*)(ws + o); o += (size_t)DIMC * DIMC * 2;
  __bf16* wkv16 = (__bf16*)(ws + o); o += (size_t)DIMC * DIMC * 2;
  __bf16* wo16 = (__bf16*)(ws + o); o += (size_t)DIMC * DIMC * 2;
  float* kvraw = (float*)(ws + o);  o += (size_t)BATCH * SEQ * DIMC * 4;
  float* qraw = (float*)(ws + o);   o += (size_t)BATCH * LATENT * DIMC * 4;
  __bf16* kvn = (__bf16*)(ws + o);  o += (size_t)BATCH * HEADS * SEQ * DHH * 2;
  __bf16* kvnT = (__bf16*)(ws + o); o += (size_t)BATCH * HEADS * SEQ * DHH * 2;
  __bf16* qb = (__bf16*)(ws + o);   o += (size_t)BATCH * HEADS * LATENT * DHH * 2;
  __bf16* aout = (__bf16*)(ws + o); o += (size_t)BATCH * LATENT * DIMC * 2;

  k_convert<<<2048, 256, 0, stream>>>(x, x16, BATCH * SEQ * DIMC);
  k_convert<<<512, 256, 0, stream>>>(Wq, wq16, DIMC * DIMC);
  k_convert<<<512, 256, 0, stream>>>(Wkv, wkv16, DIMC * DIMC);
  k_convert<<<512, 256, 0, stream>>>(Wo, wo16, DIMC * DIMC);
  k_gemm<0, 0><<<dim3(8, 64), 256, 0, stream>>>(x16, wkv16, kvraw, nullptr, 8192, 1024, 1024);
  k_gemm<1, 0><<<dim3(8, 16), 256, 0, stream>>>(x16, wq16, qraw, nullptr, 2048, 1024, 1024);
  k_epi_kv<<<2048, 256, 0, stream>>>(kvraw, kvn, kvnT, gamma, beta);
  k_epi_q<<<512, 256, 0, stream>>>(qraw, qb);
  k_flash3<<<1024, 256, 0, stream>>>(qb, kvn, kvnT, aout);
  k_gemm<0, 1><<<dim3(8, 16), 256, 0, stream>>>(aout, wo16, (float*)d_out, bo, 2048, 1024, 1024);
}

// Round 5
// 204.660 us; speedup vs baseline: 1.7049x; 1.1037x over previous
//
#include <hip/hip_runtime.h>
#include <hip/hip_bf16.h>
#include <cstdint>

#define DIMC 1024
#define HEADS 16
#define DHH 64
#define SEQ 4096
#define LATENT 1024
#define HISTC 3072
#define BATCH 2

typedef __attribute__((ext_vector_type(8))) __bf16 bf16x8;
typedef __attribute__((ext_vector_type(4))) float f32x4;
typedef __attribute__((ext_vector_type(16))) float f32x16;

// ---------------- fp32 -> bf16 convert (vectorized) ----------------
__global__ void k_convert(const float* __restrict__ in, __bf16* __restrict__ out, int n) {
  int stride = gridDim.x * blockDim.x;
  int nc = n >> 2;
  for (int i = blockIdx.x * blockDim.x + threadIdx.x; i < nc; i += stride) {
    float4 v = reinterpret_cast<const float4*>(in)[i];
    union { __bf16 h[4]; uint64_t u; } p;
    p.h[0] = (__bf16)v.x; p.h[1] = (__bf16)v.y;
    p.h[2] = (__bf16)v.z; p.h[3] = (__bf16)v.w;
    reinterpret_cast<uint64_t*>(out)[i] = p.u;
  }
}

// ---------------- async global->LDS 16B ----------------
__device__ __forceinline__ void gload16(void* lds, const void* g) {
  __builtin_amdgcn_global_load_lds(
      (const __attribute__((address_space(1))) unsigned int*)g,
      (__attribute__((address_space(3))) unsigned int*)lds, 16, 0, 0);
}

// ---------------- GEMM: C[M,N] = A[M,K] @ Bw[N,K]^T (+bias) --------
template<int QREMAP, int BIAS>
__launch_bounds__(256)
__global__ void k_gemm(const __bf16* __restrict__ A, const __bf16* __restrict__ Bw,
                       float* __restrict__ C, const float* __restrict__ bias,
                       int M, int N, int K) {
  __shared__ __align__(16) char lds[16384];
  const int t = threadIdx.x;
  const int l = t & 63, w = t >> 6;
  const int wr = w >> 1, wc = w & 1;
  const int m0 = blockIdx.y * 128, n0 = blockIdx.x * 128;
  const int lrow = l & 15, lk = l >> 4;
  f32x4 acc[4][4] = {};

  for (int k0 = 0; k0 < K; k0 += 32) {
    if (k0) __syncthreads();
#pragma unroll
    for (int i = 0; i < 2; ++i) {
      int c = i * 256 + t;
      int row = c >> 2, kc = c & 3;
      int mi = m0 + row;
      if (QREMAP) mi += HISTC + (mi >> 10) * HISTC;
      gload16(lds + c * 16, A + (size_t)mi * K + k0 + kc * 8);
      gload16(lds + 8192 + c * 16, Bw + (size_t)(n0 + row) * K + k0 + kc * 8);
    }
    __syncthreads();
    bf16x8 af[4], bfr[4];
#pragma unroll
    for (int m = 0; m < 4; ++m)
      af[m] = *reinterpret_cast<const bf16x8*>(lds + (wr * 64 + m * 16 + lrow) * 64 + lk * 16);
#pragma unroll
    for (int n = 0; n < 4; ++n)
      bfr[n] = *reinterpret_cast<const bf16x8*>(lds + 8192 + (wc * 64 + n * 16 + lrow) * 64 + lk * 16);
#pragma unroll
    for (int m = 0; m < 4; ++m)
#pragma unroll
      for (int n = 0; n < 4; ++n)
        acc[m][n] = __builtin_amdgcn_mfma_f32_16x16x32_bf16(af[m], bfr[n], acc[m][n], 0, 0, 0);
  }

#pragma unroll
  for (int m = 0; m < 4; ++m)
#pragma unroll
    for (int n = 0; n < 4; ++n)
#pragma unroll
      for (int r = 0; r < 4; ++r) {
        int row = m0 + wr * 64 + m * 16 + (l >> 4) * 4 + r;
        int col = n0 + wc * 64 + n * 16 + (l & 15);
        float v = acc[m][n][r];
        if (BIAS) v += bias[col];
        C[(size_t)row * N + col] = v;
      }
}

// ---------------- kv epilogue: RoPE + per-head LN, write kvn + kvnT ----
// kvnT columns are sigma-permuted within each 32-key tile (swap bits 2<->3 of
// the key index) so that flash's PV B-fragment is each lane's own p[] values.
__launch_bounds__(256)
__global__ void k_epi_kv(const float* __restrict__ kv_raw, __bf16* __restrict__ kvn,
                         __bf16* __restrict__ kvnT, const float* __restrict__ gamma,
                         const float* __restrict__ beta) {
  int bx = blockIdx.x;
  int nt = bx & 63, h = (bx >> 6) & 15, b = bx >> 10;
  int t = threadIdx.x, l = t & 63, w = t >> 6;
  int n0 = nt * 64;
  __shared__ __bf16 Tl[64][65];
  float g = gamma[l], be = beta[l];
  float invf = expf(-(float)(l & 31) * 0.28782313662425574f);
  float sign = (l < 32) ? -1.f : 1.f;
#pragma unroll 1
  for (int ni = 0; ni < 16; ++ni) {
    int n = n0 + w * 16 + ni;
    float v = kv_raw[(size_t)(b * SEQ + n) * DIMC + h * DHH + l];
    float sv, cv;
    sincosf((float)n * invf, &sv, &cv);
    float partner = __shfl_xor(v, 32);
    float rope = v * cv + sign * partner * sv;
    float s = rope;
#pragma unroll
    for (int xm = 1; xm < 64; xm <<= 1) s += __shfl_xor(s, xm);
    float mu = s * (1.f / 64.f);
    float d = rope - mu;
    float vs = d * d;
#pragma unroll
    for (int xm = 1; xm < 64; xm <<= 1) vs += __shfl_xor(vs, xm);
    float inv = rsqrtf(vs * (1.f / 64.f) + 1e-5f);
    float y = d * inv * g + be;
    kvn[((size_t)(b * HEADS + h) * SEQ + n) * DHH + l] = (__bf16)y;
    Tl[l][w * 16 + ni] = (__bf16)y;
  }
  __syncthreads();
  const int pp = (l & ~12) | ((l & 4) << 1) | ((l & 8) >> 1);  // swap bits 2,3
#pragma unroll 1
  for (int di = 0; di < 16; ++di) {
    int d = w * 16 + di;
    kvnT[((size_t)(b * HEADS + h) * DHH + d) * SEQ + n0 + pp] = Tl[d][l];
  }
}

// ---------------- q epilogue: RoPE + scale (incl. log2e for base-2 softmax) ----
__launch_bounds__(256)
__global__ void k_epi_q(const float* __restrict__ q_raw, __bf16* __restrict__ qb) {
  int bx = blockIdx.x;
  int it = bx & 15, h = (bx >> 4) & 15, b = bx >> 8;
  int t = threadIdx.x, l = t & 63, w = t >> 6;
  int i0 = it * 64;
  float invf = expf(-(float)(l & 31) * 0.28782313662425574f);
  float sign = (l < 32) ? -1.f : 1.f;
#pragma unroll 1
  for (int ii = 0; ii < 16; ++ii) {
    int i = i0 + w * 16 + ii;
    float v = q_raw[(size_t)(b * LATENT + i) * DIMC + h * DHH + l];
    float sv, cv;
    sincosf((float)(HISTC + i) * invf, &sv, &cv);
    float partner = __shfl_xor(v, 32);
    // DH^-0.5 * log2(e) : softmax computed base-2
    float rope = (v * cv + sign * partner * sv) * 0.18033688011112042f;
    qb[((size_t)(b * HEADS + h) * LATENT + i) * DHH + l] = (__bf16)rope;
  }
}

// ---------------- helpers for flash ----------------
__device__ __forceinline__ float fexp2(float x) {
#if __has_builtin(__builtin_amdgcn_exp2f)
  return __builtin_amdgcn_exp2f(x);
#else
  return exp2f(x);
#endif
}

__device__ __forceinline__ unsigned pk2(float a, float b) {
  union { __bf16 h[2]; unsigned u; } x;
  x.h[0] = (__bf16)a; x.h[1] = (__bf16)b;
  return x.u;
}

// ---------------- flash attention v4 ----------------
// 1D grid 1024, XCD-aware: xcd = bid&7, 4 (b,h) groups per XCD.
// Per block: 32 q-rows, 4 waves split the j-range (merged via LDS).
// kvnT is sigma-permuted -> PV B-frag = lane's own p[] (no cross-lane exchange).
// K and V register-prefetched one tile ahead. Per-wave LDS region is a union
// of the V staging tile and the O merge buffer (never live simultaneously).
__launch_bounds__(256)
__global__ void k_flash4(const __bf16* __restrict__ qb, const __bf16* __restrict__ kvn,
                         const __bf16* __restrict__ kvnT, __bf16* __restrict__ aout) {
  const int bid = blockIdx.x;
  const int bh = (bid & 7) + 8 * (bid >> 8);      // group -> same XCD for all 32 itiles
  const int itile = (bid >> 3) & 31;
  const int h = bh & 15, b = bh >> 4;
  const int t = threadIdx.x, l = t & 63, w = t >> 6;
  const int q = l & 31, hi = l >> 5;
  const int iw = itile * 32;
  const int i = iw + q;
  const __bf16* qbase = qb + ((size_t)(b * HEADS + h) * LATENT + iw) * DHH;
  const __bf16* kbase = kvn + (size_t)(b * HEADS + h) * SEQ * DHH;
  const __bf16* vbase = kvnT + (size_t)(b * HEADS + h) * DHH * SEQ;

  __shared__ __align__(16) char smem[4][5120];     // per-wave: V tile [64][40]bf16 | O merge [32][33]f32
  __shared__ float Mlds[4][32];
  __shared__ float Llds[4][32];
  __bf16 (*Vw)[40] = reinterpret_cast<__bf16(*)[40]>(smem[w]);

  // Q as B-operand: col=lane&31=q-row, k=(lane>>5)*8+e
  bf16x8 qf[4];
#pragma unroll
  for (int c = 0; c < 4; ++c)
    qf[c] = *reinterpret_cast<const bf16x8*>(qbase + (size_t)q * DHH + c * 16 + hi * 8);

  f32x16 O0 = {}, O1 = {};
  float m_run = -INFINITY, l_run = 0.f;

  const int nt = itile + 97;               // tiles of 32 keys
  const int t0 = (nt * w) >> 2, t1 = (nt * (w + 1)) >> 2;

  // staging pattern: lane covers V^T row (ii*16 + l>>2), key-chunk (l&3)*8
  const int srow = l >> 2, scol = l & 3;
  bf16x8 vreg[4], kreg[4];
#pragma unroll
  for (int ii = 0; ii < 4; ++ii)
    vreg[ii] = *reinterpret_cast<const bf16x8*>(
        vbase + (size_t)(ii * 16 + srow) * SEQ + t0 * 32 + scol * 8);
#pragma unroll
  for (int c = 0; c < 4; ++c)
    kreg[c] = *reinterpret_cast<const bf16x8*>(
        kbase + (size_t)(t0 * 32 + q) * DHH + c * 16 + hi * 8);

  for (int tt = t0; tt < t1; ++tt) {
    const int j0 = tt * 32;
    // commit V(tt) to this wave's LDS region (wave-private, DS ops in-order per wave)
#pragma unroll
    for (int ii = 0; ii < 4; ++ii)
      *reinterpret_cast<bf16x8*>(&Vw[ii * 16 + srow][scol * 8]) = vreg[ii];
    bf16x8 kc[4];
#pragma unroll
    for (int c = 0; c < 4; ++c) kc[c] = kreg[c];
    // prefetch K/V(tt+1): latency hides under this tile's compute
    if (tt + 1 < t1) {
#pragma unroll
      for (int ii = 0; ii < 4; ++ii)
        vreg[ii] = *reinterpret_cast<const bf16x8*>(
            vbase + (size_t)(ii * 16 + srow) * SEQ + (tt + 1) * 32 + scol * 8);
#pragma unroll
      for (int c = 0; c < 4; ++c)
        kreg[c] = *reinterpret_cast<const bf16x8*>(
            kbase + (size_t)((tt + 1) * 32 + q) * DHH + c * 16 + hi * 8);
    }
    // QK^T swapped: S[key][qrow]
    f32x16 S = {};
#pragma unroll
    for (int c = 0; c < 4; ++c)
      S = __builtin_amdgcn_mfma_f32_32x32x16_bf16(kc[c], qf[c], S, 0, 0, 0);
    if (j0 + 31 > iw + HISTC) {            // mask: j - HIST > i
#pragma unroll
      for (int r = 0; r < 16; ++r) {
        int j = j0 + (r & 3) + 8 * (r >> 2) + 4 * hi;
        if (j > i + HISTC) S[r] = -1e30f;
      }
    }
    // row max: in-lane tree + one partner exchange
    float a8[8];
#pragma unroll
    for (int r = 0; r < 8; ++r) a8[r] = fmaxf(S[r], S[r + 8]);
    float a4_0 = fmaxf(a8[0], a8[4]), a4_1 = fmaxf(a8[1], a8[5]);
    float a4_2 = fmaxf(a8[2], a8[6]), a4_3 = fmaxf(a8[3], a8[7]);
    float pm = fmaxf(fmaxf(a4_0, a4_1), fmaxf(a4_2, a4_3));
    pm = fmaxf(pm, __shfl_xor(pm, 32));
    // defer-max (T13), log2 units; P <= 2^8
    if (__any(pm > m_run + 8.0f)) {
      float mn = fmaxf(m_run, pm);
      float sc = fexp2(m_run - mn);        // first tile: exp2(-inf)=0
      m_run = mn;
      l_run *= sc;
#pragma unroll
      for (int r = 0; r < 16; ++r) { O0[r] *= sc; O1[r] *= sc; }
    }
    // P = 2^(S - m), row sum
    float p[16];
#pragma unroll
    for (int r = 0; r < 16; ++r) p[r] = fexp2(S[r] - m_run);
    float s8[8];
#pragma unroll
    for (int r = 0; r < 8; ++r) s8[r] = p[r] + p[r + 8];
    float s4_0 = s8[0] + s8[4], s4_1 = s8[1] + s8[5];
    float s4_2 = s8[2] + s8[6], s4_3 = s8[3] + s8[7];
    float ssum = (s4_0 + s4_1) + (s4_2 + s4_3);
    l_run += ssum + __shfl_xor(ssum, 32);
    // PV B-frags = own p's (sigma-permuted V absorbs the layout exchange)
    union { unsigned u[4]; bf16x8 v; } pf0, pf1;
    pf0.u[0] = pk2(p[0], p[1]);   pf0.u[1] = pk2(p[2], p[3]);
    pf0.u[2] = pk2(p[4], p[5]);   pf0.u[3] = pk2(p[6], p[7]);
    pf1.u[0] = pk2(p[8], p[9]);   pf1.u[1] = pk2(p[10], p[11]);
    pf1.u[2] = pk2(p[12], p[13]); pf1.u[3] = pk2(p[14], p[15]);
    // PV: V^T frags from this wave's LDS tile
    {
      bf16x8 va00 = *reinterpret_cast<const bf16x8*>(&Vw[q][hi * 8]);
      bf16x8 va01 = *reinterpret_cast<const bf16x8*>(&Vw[q][16 + hi * 8]);
      bf16x8 va10 = *reinterpret_cast<const bf16x8*>(&Vw[32 + q][hi * 8]);
      bf16x8 va11 = *reinterpret_cast<const bf16x8*>(&Vw[32 + q][16 + hi * 8]);
      O0 = __builtin_amdgcn_mfma_f32_32x32x16_bf16(va00, pf0.v, O0, 0, 0, 0);
      O0 = __builtin_amdgcn_mfma_f32_32x32x16_bf16(va01, pf1.v, O0, 0, 0, 0);
      O1 = __builtin_amdgcn_mfma_f32_32x32x16_bf16(va10, pf0.v, O1, 0, 0, 0);
      O1 = __builtin_amdgcn_mfma_f32_32x32x16_bf16(va11, pf1.v, O1, 0, 0, 0);
    }
  }

  // -------- merge the 4 waves' partial (O, m, l), chunked over d --------
  float (*Ow)[33] = reinterpret_cast<float(*)[33]>(smem[w]);   // union with Vw (V dead now)
  if (hi == 0) { Mlds[w][q] = m_run; Llds[w][q] = l_run; }
#pragma unroll
  for (int r = 0; r < 16; ++r)
    Ow[q][(r & 3) + 8 * (r >> 2) + 4 * hi] = O0[r];
  __syncthreads();
  const int mi = t >> 3, dl = (t & 7) * 4;
  float m0v = Mlds[0][mi], m1v = Mlds[1][mi], m2v = Mlds[2][mi], m3v = Mlds[3][mi];
  float mm = fmaxf(fmaxf(m0v, m1v), fmaxf(m2v, m3v));
  float sc0 = fexp2(m0v - mm), sc1 = fexp2(m1v - mm);
  float sc2 = fexp2(m2v - mm), sc3 = fexp2(m3v - mm);
  float ll = Llds[0][mi] * sc0 + Llds[1][mi] * sc1 + Llds[2][mi] * sc2 + Llds[3][mi] * sc3;
  float inv = 1.f / ll;
  __bf16* orow = aout + ((size_t)(b * LATENT) + iw + mi) * DIMC + h * DHH;
  {
    float(*O0p)[33] = reinterpret_cast<float(*)[33]>(smem[0]);
    float(*O1p)[33] = reinterpret_cast<float(*)[33]>(smem[1]);
    float(*O2p)[33] = reinterpret_cast<float(*)[33]>(smem[2]);
    float(*O3p)[33] = reinterpret_cast<float(*)[33]>(smem[3]);
    union { __bf16 hh[4]; uint2 u2; } pkv;
#pragma unroll
    for (int e = 0; e < 4; ++e) {
      float o = O0p[mi][dl + e] * sc0 + O1p[mi][dl + e] * sc1 +
                O2p[mi][dl + e] * sc2 + O3p[mi][dl + e] * sc3;
      pkv.hh[e] = (__bf16)(o * inv);
    }
    *reinterpret_cast<uint2*>(orow + dl) = pkv.u2;
  }
  __syncthreads();
#pragma unroll
  for (int r = 0; r < 16; ++r)
    Ow[q][(r & 3) + 8 * (r >> 2) + 4 * hi] = O1[r];
  __syncthreads();
  {
    float(*O0p)[33] = reinterpret_cast<float(*)[33]>(smem[0]);
    float(*O1p)[33] = reinterpret_cast<float(*)[33]>(smem[1]);
    float(*O2p)[33] = reinterpret_cast<float(*)[33]>(smem[2]);
    float(*O3p)[33] = reinterpret_cast<float(*)[33]>(smem[3]);
    union { __bf16 hh[4]; uint2 u2; } pkv;
#pragma unroll
    for (int e = 0; e < 4; ++e) {
      float o = O0p[mi][dl + e] * sc0 + O1p[mi][dl + e] * sc1 +
                O2p[mi][dl + e] * sc2 + O3p[mi][dl + e] * sc3;
      pkv.hh[e] = (__bf16)(o * inv);
    }
    *reinterpret_cast<uint2*>(orow + 32 + dl) = pkv.u2;
  }
}

// ---------------- host launcher ----------------
extern "C" void kernel_launch(void* const* d_in, const int* in_sizes, int n_in,
                              void* d_out, int out_size, void* d_ws, size_t ws_size,
                              hipStream_t stream) {
  const float* x = (const float*)d_in[0];
  const float* Wq = (const float*)d_in[1];
  const float* Wkv = (const float*)d_in[2];
  const float* Wo = (const float*)d_in[3];
  const float* bo = (const float*)d_in[4];
  const float* gamma = (const float*)d_in[5];
  const float* beta = (const float*)d_in[6];

  char* ws = (char*)d_ws;
  size_t o = 0;
  __bf16* x16 = (__bf16*)(ws + o);  o += (size_t)BATCH * SEQ * DIMC * 2;
  __bf16* wq16 = (__bf16*)(ws + o); o += (size_t)DIMC * DIMC * 2;
  __bf16* wkv16 = (__bf16*)(ws + o); o += (size_t)DIMC * DIMC * 2;
  __bf16* wo16 = (__bf16*)(ws + o); o += (size_t)DIMC * DIMC * 2;
  float* kvraw = (float*)(ws + o);  o += (size_t)BATCH * SEQ * DIMC * 4;
  float* qraw = (float*)(ws + o);   o += (size_t)BATCH * LATENT * DIMC * 4;
  __bf16* kvn = (__bf16*)(ws + o);  o += (size_t)BATCH * HEADS * SEQ * DHH * 2;
  __bf16* kvnT = (__bf16*)(ws + o); o += (size_t)BATCH * HEADS * SEQ * DHH * 2;
  __bf16* qb = (__bf16*)(ws + o);   o += (size_t)BATCH * HEADS * LATENT * DHH * 2;
  __bf16* aout = (__bf16*)(ws + o); o += (size_t)BATCH * LATENT * DIMC * 2;

  k_convert<<<2048, 256, 0, stream>>>(x, x16, BATCH * SEQ * DIMC);
  k_convert<<<512, 256, 0, stream>>>(Wq, wq16, DIMC * DIMC);
  k_convert<<<512, 256, 0, stream>>>(Wkv, wkv16, DIMC * DIMC);
  k_convert<<<512, 256, 0, stream>>>(Wo, wo16, DIMC * DIMC);
  k_gemm<0, 0><<<dim3(8, 64), 256, 0, stream>>>(x16, wkv16, kvraw, nullptr, 8192, 1024, 1024);
  k_gemm<1, 0><<<dim3(8, 16), 256, 0, stream>>>(x16, wq16, qraw, nullptr, 2048, 1024, 1024);
  k_epi_kv<<<2048, 256, 0, stream>>>(kvraw, kvn, kvnT, gamma, beta);
  k_epi_q<<<512, 256, 0, stream>>>(qraw, qb);
  k_flash4<<<1024, 256, 0, stream>>>(qb, kvn, kvnT, aout);
  k_gemm<0, 1><<<dim3(8, 16), 256, 0, stream>>>(aout, wo16, (float*)d_out, bo, 2048, 1024, 1024);
}

// Round 6
// 173.368 us; speedup vs baseline: 2.0126x; 1.1805x over previous
//
#include <hip/hip_runtime.h>
#include <hip/hip_bf16.h>
#include <cstdint>

#define DIMC 1024
#define HEADS 16
#define DHH 64
#define SEQ 4096
#define LATENT 1024
#define HISTC 3072
#define BATCH 2

typedef __attribute__((ext_vector_type(8))) __bf16 bf16x8;
typedef __attribute__((ext_vector_type(4))) float f32x4;
typedef __attribute__((ext_vector_type(16))) float f32x16;

// ---------------- fp32 -> bf16 convert (vectorized) ----------------
__global__ void k_convert(const float* __restrict__ in, __bf16* __restrict__ out, int n) {
  int stride = gridDim.x * blockDim.x;
  int nc = n >> 2;
  for (int i = blockIdx.x * blockDim.x + threadIdx.x; i < nc; i += stride) {
    float4 v = reinterpret_cast<const float4*>(in)[i];
    union { __bf16 h[4]; uint64_t u; } p;
    p.h[0] = (__bf16)v.x; p.h[1] = (__bf16)v.y;
    p.h[2] = (__bf16)v.z; p.h[3] = (__bf16)v.w;
    reinterpret_cast<uint64_t*>(out)[i] = p.u;
  }
}

// three weight matrices (1024x1024 each) in one launch
__global__ void k_convert3(const float* __restrict__ a, const float* __restrict__ b,
                           const float* __restrict__ c, __bf16* __restrict__ oa,
                           __bf16* __restrict__ ob, __bf16* __restrict__ oc) {
  int id = blockIdx.x;
  const float* src; __bf16* dst;
  if (id < 512) { src = a; dst = oa; }
  else if (id < 1024) { src = b; dst = ob; id -= 512; }
  else { src = c; dst = oc; id -= 1024; }
#pragma unroll
  for (int k = 0; k < 2; ++k) {
    int idx = id * 512 + k * 256 + threadIdx.x;
    float4 v = reinterpret_cast<const float4*>(src)[idx];
    union { __bf16 h[4]; uint64_t u; } p;
    p.h[0] = (__bf16)v.x; p.h[1] = (__bf16)v.y;
    p.h[2] = (__bf16)v.z; p.h[3] = (__bf16)v.w;
    reinterpret_cast<uint64_t*>(dst)[idx] = p.u;
  }
}

// ---------------- async global->LDS 16B ----------------
__device__ __forceinline__ void gload16(void* lds, const void* g) {
  __builtin_amdgcn_global_load_lds(
      (const __attribute__((address_space(1))) unsigned int*)g,
      (__attribute__((address_space(3))) unsigned int*)lds, 16, 0, 0);
}

// ---------------- plain GEMM (used for o-proj): C = A @ Bw^T + bias ----
template<int QREMAP, int BIAS>
__launch_bounds__(256)
__global__ void k_gemm(const __bf16* __restrict__ A, const __bf16* __restrict__ Bw,
                       float* __restrict__ C, const float* __restrict__ bias,
                       int M, int N, int K) {
  __shared__ __align__(16) char lds[16384];
  const int t = threadIdx.x;
  const int l = t & 63, w = t >> 6;
  const int wr = w >> 1, wc = w & 1;
  const int m0 = blockIdx.y * 128, n0 = blockIdx.x * 128;
  const int lrow = l & 15, lk = l >> 4;
  f32x4 acc[4][4] = {};

  for (int k0 = 0; k0 < K; k0 += 32) {
    if (k0) __syncthreads();
#pragma unroll
    for (int i = 0; i < 2; ++i) {
      int c = i * 256 + t;
      int row = c >> 2, kc = c & 3;
      int mi = m0 + row;
      if (QREMAP) mi += HISTC + (mi >> 10) * HISTC;
      gload16(lds + c * 16, A + (size_t)mi * K + k0 + kc * 8);
      gload16(lds + 8192 + c * 16, Bw + (size_t)(n0 + row) * K + k0 + kc * 8);
    }
    __syncthreads();
    bf16x8 af[4], bfr[4];
#pragma unroll
    for (int m = 0; m < 4; ++m)
      af[m] = *reinterpret_cast<const bf16x8*>(lds + (wr * 64 + m * 16 + lrow) * 64 + lk * 16);
#pragma unroll
    for (int n = 0; n < 4; ++n)
      bfr[n] = *reinterpret_cast<const bf16x8*>(lds + 8192 + (wc * 64 + n * 16 + lrow) * 64 + lk * 16);
#pragma unroll
    for (int m = 0; m < 4; ++m)
#pragma unroll
      for (int n = 0; n < 4; ++n)
        acc[m][n] = __builtin_amdgcn_mfma_f32_16x16x32_bf16(af[m], bfr[n], acc[m][n], 0, 0, 0);
  }

#pragma unroll
  for (int m = 0; m < 4; ++m)
#pragma unroll
    for (int n = 0; n < 4; ++n)
#pragma unroll
      for (int r = 0; r < 4; ++r) {
        int row = m0 + wr * 64 + m * 16 + (l >> 4) * 4 + r;
        int col = n0 + wc * 64 + n * 16 + (l & 15);
        float v = acc[m][n][r];
        if (BIAS) v += bias[col];
        C[(size_t)row * N + col] = v;
      }
}

// ---------------- fused QKV GEMM: kv-proj(+RoPE+LN) and q-proj(+RoPE+scale) ----
// grid (8, 80): by<64 -> kv rows (M=8192), by>=64 -> q rows (M=2048, remapped).
// Epilogue entirely in registers: rotate-half partner (d+-32) = acc[m][n^2][r]
// (same lane); LN reduces across the 16 lanes sharing an output row.
__launch_bounds__(256)
__global__ void k_gemmqkv(const __bf16* __restrict__ x16,
                          const __bf16* __restrict__ wkv16,
                          const __bf16* __restrict__ wq16,
                          __bf16* __restrict__ kvn, __bf16* __restrict__ kvnT,
                          __bf16* __restrict__ qb,
                          const float* __restrict__ gamma,
                          const float* __restrict__ beta) {
  __shared__ __align__(16) char lds[16384];
  const int t = threadIdx.x, l = t & 63, w = t >> 6;
  const int wr = w >> 1, wc = w & 1;
  const int by = blockIdx.y;
  const bool isq = by >= 64;
  const int m0 = (isq ? (by - 64) : by) * 128;
  const int n0 = blockIdx.x * 128;
  const __bf16* Bw = isq ? wq16 : wkv16;
  const int lrow = l & 15, lk = l >> 4;
  f32x4 acc[4][4] = {};

  for (int k0 = 0; k0 < 1024; k0 += 32) {
    if (k0) __syncthreads();
#pragma unroll
    for (int i = 0; i < 2; ++i) {
      int c = i * 256 + t;
      int row = c >> 2, kc = c & 3;
      int mi = m0 + row;
      if (isq) mi += HISTC + (mi >> 10) * HISTC;
      gload16(lds + c * 16, x16 + (size_t)mi * 1024 + k0 + kc * 8);
      gload16(lds + 8192 + c * 16, Bw + (size_t)(n0 + row) * 1024 + k0 + kc * 8);
    }
    __syncthreads();
    bf16x8 af[4], bfr[4];
#pragma unroll
    for (int m = 0; m < 4; ++m)
      af[m] = *reinterpret_cast<const bf16x8*>(lds + (wr * 64 + m * 16 + lrow) * 64 + lk * 16);
#pragma unroll
    for (int n = 0; n < 4; ++n)
      bfr[n] = *reinterpret_cast<const bf16x8*>(lds + 8192 + (wc * 64 + n * 16 + lrow) * 64 + lk * 16);
#pragma unroll
    for (int m = 0; m < 4; ++m)
#pragma unroll
      for (int n = 0; n < 4; ++n)
        acc[m][n] = __builtin_amdgcn_mfma_f32_16x16x32_bf16(af[m], bfr[n], acc[m][n], 0, 0, 0);
  }

  // ---- RoPE in place (pairs (0,2) and (1,3) share one lane) ----
  // inv_freq = 10000^(-f/32), f = d&31; d = n*16+lrow -> f = (n&1)*16+lrow
  const float LG = 0.41524101186f;               // log2(10000)/32
  float invf0 = exp2f(-(float)lrow * LG);
  float invf1 = exp2f(-(float)(lrow + 16) * LG);
#pragma unroll
  for (int m = 0; m < 4; ++m)
#pragma unroll
    for (int r = 0; r < 4; ++r) {
      int rl = wr * 64 + m * 16 + lk * 4 + r;
      int pos = isq ? (HISTC + ((m0 + rl) & 1023)) : ((m0 + rl) & 4095);
      float fp = (float)pos;
      float s0, c0, s1, c1;
      sincosf(fp * invf0, &s0, &c0);
      sincosf(fp * invf1, &s1, &c1);
      float a0 = acc[m][0][r], a2 = acc[m][2][r];
      acc[m][0][r] = a0 * c0 - a2 * s0;
      acc[m][2][r] = a2 * c0 + a0 * s0;
      float a1 = acc[m][1][r], a3 = acc[m][3][r];
      acc[m][1][r] = a1 * c1 - a3 * s1;
      acc[m][3][r] = a3 * c1 + a1 * s1;
    }

  const int h = (n0 + wc * 64) >> 6;
  if (!isq) {
    // ---- per-head LayerNorm over the 64 cols (16-lane reduction) ----
    float g4[4], b4[4];
#pragma unroll
    for (int n = 0; n < 4; ++n) { g4[n] = gamma[n * 16 + lrow]; b4[n] = beta[n * 16 + lrow]; }
#pragma unroll
    for (int m = 0; m < 4; ++m)
#pragma unroll
      for (int r = 0; r < 4; ++r) {
        float s1 = acc[m][0][r] + acc[m][1][r] + acc[m][2][r] + acc[m][3][r];
        float s2 = acc[m][0][r] * acc[m][0][r] + acc[m][1][r] * acc[m][1][r] +
                   acc[m][2][r] * acc[m][2][r] + acc[m][3][r] * acc[m][3][r];
#pragma unroll
        for (int mk = 1; mk < 16; mk <<= 1) {
          s1 += __shfl_xor(s1, mk);
          s2 += __shfl_xor(s2, mk);
        }
        float mu = s1 * 0.015625f;
        float var = s2 * 0.015625f - mu * mu;
        float inv = rsqrtf(var + 1e-5f);
#pragma unroll
        for (int n = 0; n < 4; ++n)
          acc[m][n][r] = (acc[m][n][r] - mu) * inv * g4[n] + b4[n];
      }
    const size_t hb = (size_t)((m0 >> 12) * HEADS + h);
    // kvn [b,h,pos,d]
#pragma unroll
    for (int m = 0; m < 4; ++m)
#pragma unroll
      for (int r = 0; r < 4; ++r) {
        int pos = (m0 + wr * 64 + m * 16 + lk * 4 + r) & 4095;
#pragma unroll
        for (int n = 0; n < 4; ++n)
          kvn[(hb * SEQ + pos) * DHH + n * 16 + lrow] = (__bf16)acc[m][n][r];
      }
    // kvnT [b,h,d,sigma(pos)] : r-quads stay contiguous under sigma (bits 2,3 swap)
#pragma unroll
    for (int m = 0; m < 4; ++m) {
      int pos0 = (m0 + wr * 64 + m * 16 + lk * 4) & 4095;
      int sp = (pos0 & ~12) | ((pos0 & 4) << 1) | ((pos0 & 8) >> 1);
#pragma unroll
      for (int n = 0; n < 4; ++n) {
        union { __bf16 hh[4]; uint64_t u; } pk;
#pragma unroll
        for (int r = 0; r < 4; ++r) pk.hh[r] = (__bf16)acc[m][n][r];
        *reinterpret_cast<uint64_t*>(kvnT + (hb * DHH + n * 16 + lrow) * SEQ + sp) = pk.u;
      }
    }
  } else {
    // ---- q: scale by DH^-0.5 * log2(e), write qb [b,h,i,d] ----
    const size_t hb = (size_t)((m0 >> 10) * HEADS + h);
#pragma unroll
    for (int m = 0; m < 4; ++m)
#pragma unroll
      for (int r = 0; r < 4; ++r) {
        int qi = (m0 + wr * 64 + m * 16 + lk * 4 + r) & 1023;
#pragma unroll
        for (int n = 0; n < 4; ++n)
          qb[(hb * LATENT + qi) * DHH + n * 16 + lrow] =
              (__bf16)(acc[m][n][r] * 0.18033688011112042f);
      }
  }
}

// ---------------- helpers for flash ----------------
__device__ __forceinline__ float fexp2(float x) {
#if __has_builtin(__builtin_amdgcn_exp2f)
  return __builtin_amdgcn_exp2f(x);
#else
  return exp2f(x);
#endif
}

__device__ __forceinline__ unsigned pk2(float a, float b) {
  union { __bf16 h[2]; unsigned u; } x;
  x.h[0] = (__bf16)a; x.h[1] = (__bf16)b;
  return x.u;
}

// ---------------- flash attention v5 ----------------
// As flash4 (XCD-pinned, swapped QK^T, sigma-permuted V) plus:
// - XOR-swizzled V tile [64][32] (conflict-free ds write+read)
// - S seeded from persistent zero vector (no per-tile C-init movs)
// - MFMA-before-prefetch ordering (no kc register copies)
// - lane-local l accumulation (one shfl after the loop, none per tile)
// - max shuffle only inside the rare rescale branch; max3-friendly tree
__launch_bounds__(256)
__global__ void k_flash5(const __bf16* __restrict__ qb, const __bf16* __restrict__ kvn,
                         const __bf16* __restrict__ kvnT, __bf16* __restrict__ aout) {
  const int bid = blockIdx.x;
  const int bh = (bid & 7) + 8 * (bid >> 8);
  const int itile = (bid >> 3) & 31;
  const int h = bh & 15, b = bh >> 4;
  const int t = threadIdx.x, l = t & 63, w = t >> 6;
  const int q = l & 31, hi = l >> 5;
  const int iw = itile * 32;
  const int i = iw + q;
  const __bf16* qbase = qb + ((size_t)(b * HEADS + h) * LATENT + iw) * DHH;
  const __bf16* kbase = kvn + (size_t)(b * HEADS + h) * SEQ * DHH;
  const __bf16* vbase = kvnT + (size_t)(b * HEADS + h) * DHH * SEQ;

  __shared__ __align__(16) char smem[4][4352];   // per-wave: V [64][32]bf16 | O merge [32][33]f32
  __shared__ float Mlds[4][32];
  __shared__ float Llds[4][32];
  __bf16 (*Vw)[32] = reinterpret_cast<__bf16(*)[32]>(smem[w]);

  bf16x8 qf[4];
#pragma unroll
  for (int c = 0; c < 4; ++c)
    qf[c] = *reinterpret_cast<const bf16x8*>(qbase + (size_t)q * DHH + c * 16 + hi * 8);

  const f32x16 Z = {};
  f32x16 O0 = {}, O1 = {};
  float m_run = -INFINITY, lacc = 0.f;

  const int nt = itile + 97;
  const int t0 = (nt * w) >> 2, t1 = (nt * (w + 1)) >> 2;

  const int srow = l >> 2, scol = l & 3;
  const int wchunk = (scol ^ (srow & 3)) * 8;    // XOR-swizzled 16B chunk slot
  const int sx = q & 3;
  bf16x8 vreg[4], kreg[4];
#pragma unroll
  for (int ii = 0; ii < 4; ++ii)
    vreg[ii] = *reinterpret_cast<const bf16x8*>(
        vbase + (size_t)(ii * 16 + srow) * SEQ + t0 * 32 + scol * 8);
#pragma unroll
  for (int c = 0; c < 4; ++c)
    kreg[c] = *reinterpret_cast<const bf16x8*>(
        kbase + (size_t)(t0 * 32 + q) * DHH + c * 16 + hi * 8);

  for (int tt = t0; tt < t1; ++tt) {
    const int j0 = tt * 32;
    // QK^T first (consumes kreg at issue; prefetch can then overwrite)
    f32x16 S = __builtin_amdgcn_mfma_f32_32x32x16_bf16(kreg[0], qf[0], Z, 0, 0, 0);
#pragma unroll
    for (int c = 1; c < 4; ++c)
      S = __builtin_amdgcn_mfma_f32_32x32x16_bf16(kreg[c], qf[c], S, 0, 0, 0);
    // commit V(tt) into swizzled LDS (wave-private)
#pragma unroll
    for (int ii = 0; ii < 4; ++ii)
      *reinterpret_cast<bf16x8*>(&Vw[ii * 16 + srow][wchunk]) = vreg[ii];
    // branchless clamped prefetch of tile tt+1
    const int tn = (tt + 1 < t1) ? tt + 1 : tt;
#pragma unroll
    for (int ii = 0; ii < 4; ++ii)
      vreg[ii] = *reinterpret_cast<const bf16x8*>(
          vbase + (size_t)(ii * 16 + srow) * SEQ + tn * 32 + scol * 8);
#pragma unroll
    for (int c = 0; c < 4; ++c)
      kreg[c] = *reinterpret_cast<const bf16x8*>(
          kbase + (size_t)(tn * 32 + q) * DHH + c * 16 + hi * 8);
    // mask: j - HIST > i
    if (j0 + 31 > iw + HISTC) {
#pragma unroll
      for (int r = 0; r < 16; ++r) {
        int j = j0 + (r & 3) + 8 * (r >> 2) + 4 * hi;
        if (j > i + HISTC) S[r] = -1e30f;
      }
    }
    // lane-local max (max3-friendly tree, 8 ops)
    float u1 = fmaxf(fmaxf(S[0], S[1]), S[2]);
    float u2 = fmaxf(fmaxf(S[3], S[4]), S[5]);
    float u3 = fmaxf(fmaxf(S[6], S[7]), S[8]);
    float u4 = fmaxf(fmaxf(S[9], S[10]), S[11]);
    float u5 = fmaxf(fmaxf(S[12], S[13]), S[14]);
    float pm = fmaxf(fmaxf(fmaxf(u1, u2), u3), fmaxf(fmaxf(u4, u5), S[15]));
    // defer-max: rescale (and sync the halves' max) only when needed
    if (__any(pm > m_run + 8.0f)) {
      pm = fmaxf(pm, __shfl_xor(pm, 32));
      float mn = fmaxf(m_run, pm);
      float sc = fexp2(m_run - mn);          // first tile: exp2(-inf)=0
      m_run = mn;
      lacc *= sc;
#pragma unroll
      for (int r = 0; r < 16; ++r) { O0[r] *= sc; O1[r] *= sc; }
    }
    // P = 2^(S-m); lane-local sum into lacc (no per-tile shuffle)
    float p[16];
#pragma unroll
    for (int r = 0; r < 16; ++r) p[r] = fexp2(S[r] - m_run);
    float s8[8];
#pragma unroll
    for (int r = 0; r < 8; ++r) s8[r] = p[r] + p[r + 8];
    float s4_0 = s8[0] + s8[4], s4_1 = s8[1] + s8[5];
    float s4_2 = s8[2] + s8[6], s4_3 = s8[3] + s8[7];
    lacc += (s4_0 + s4_1) + (s4_2 + s4_3);
    // PV B-frags = own p's (sigma-permuted V absorbs the exchange)
    union { unsigned u[4]; bf16x8 v; } pf0, pf1;
    pf0.u[0] = pk2(p[0], p[1]);   pf0.u[1] = pk2(p[2], p[3]);
    pf0.u[2] = pk2(p[4], p[5]);   pf0.u[3] = pk2(p[6], p[7]);
    pf1.u[0] = pk2(p[8], p[9]);   pf1.u[1] = pk2(p[10], p[11]);
    pf1.u[2] = pk2(p[12], p[13]); pf1.u[3] = pk2(p[14], p[15]);
    // PV from swizzled LDS (logical chunk c at row rr lives at chunk c^(rr&3))
    {
      bf16x8 va00 = *reinterpret_cast<const bf16x8*>(&Vw[q][(hi ^ sx) * 8]);
      bf16x8 va01 = *reinterpret_cast<const bf16x8*>(&Vw[q][((2 + hi) ^ sx) * 8]);
      bf16x8 va10 = *reinterpret_cast<const bf16x8*>(&Vw[32 + q][(hi ^ sx) * 8]);
      bf16x8 va11 = *reinterpret_cast<const bf16x8*>(&Vw[32 + q][((2 + hi) ^ sx) * 8]);
      O0 = __builtin_amdgcn_mfma_f32_32x32x16_bf16(va00, pf0.v, O0, 0, 0, 0);
      O0 = __builtin_amdgcn_mfma_f32_32x32x16_bf16(va01, pf1.v, O0, 0, 0, 0);
      O1 = __builtin_amdgcn_mfma_f32_32x32x16_bf16(va10, pf0.v, O1, 0, 0, 0);
      O1 = __builtin_amdgcn_mfma_f32_32x32x16_bf16(va11, pf1.v, O1, 0, 0, 0);
    }
  }
  float l_run = lacc + __shfl_xor(lacc, 32);

  // -------- merge the 4 waves' partial (O, m, l), chunked over d --------
  float (*Ow)[33] = reinterpret_cast<float(*)[33]>(smem[w]);
  if (hi == 0) { Mlds[w][q] = m_run; Llds[w][q] = l_run; }
#pragma unroll
  for (int r = 0; r < 16; ++r)
    Ow[q][(r & 3) + 8 * (r >> 2) + 4 * hi] = O0[r];
  __syncthreads();
  const int mi = t >> 3, dl = (t & 7) * 4;
  float m0v = Mlds[0][mi], m1v = Mlds[1][mi], m2v = Mlds[2][mi], m3v = Mlds[3][mi];
  float mm = fmaxf(fmaxf(m0v, m1v), fmaxf(m2v, m3v));
  float sc0 = fexp2(m0v - mm), sc1 = fexp2(m1v - mm);
  float sc2 = fexp2(m2v - mm), sc3 = fexp2(m3v - mm);
  float ll = Llds[0][mi] * sc0 + Llds[1][mi] * sc1 + Llds[2][mi] * sc2 + Llds[3][mi] * sc3;
  float inv = 1.f / ll;
  __bf16* orow = aout + ((size_t)(b * LATENT) + iw + mi) * DIMC + h * DHH;
  {
    float(*O0p)[33] = reinterpret_cast<float(*)[33]>(smem[0]);
    float(*O1p)[33] = reinterpret_cast<float(*)[33]>(smem[1]);
    float(*O2p)[33] = reinterpret_cast<float(*)[33]>(smem[2]);
    float(*O3p)[33] = reinterpret_cast<float(*)[33]>(smem[3]);
    union { __bf16 hh[4]; uint2 u2; } pkv;
#pragma unroll
    for (int e = 0; e < 4; ++e) {
      float o = O0p[mi][dl + e] * sc0 + O1p[mi][dl + e] * sc1 +
                O2p[mi][dl + e] * sc2 + O3p[mi][dl + e] * sc3;
      pkv.hh[e] = (__bf16)(o * inv);
    }
    *reinterpret_cast<uint2*>(orow + dl) = pkv.u2;
  }
  __syncthreads();
#pragma unroll
  for (int r = 0; r < 16; ++r)
    Ow[q][(r & 3) + 8 * (r >> 2) + 4 * hi] = O1[r];
  __syncthreads();
  {
    float(*O0p)[33] = reinterpret_cast<float(*)[33]>(smem[0]);
    float(*O1p)[33] = reinterpret_cast<float(*)[33]>(smem[1]);
    float(*O2p)[33] = reinterpret_cast<float(*)[33]>(smem[2]);
    float(*O3p)[33] = reinterpret_cast<float(*)[33]>(smem[3]);
    union { __bf16 hh[4]; uint2 u2; } pkv;
#pragma unroll
    for (int e = 0; e < 4; ++e) {
      float o = O0p[mi][dl + e] * sc0 + O1p[mi][dl + e] * sc1 +
                O2p[mi][dl + e] * sc2 + O3p[mi][dl + e] * sc3;
      pkv.hh[e] = (__bf16)(o * inv);
    }
    *reinterpret_cast<uint2*>(orow + 32 + dl) = pkv.u2;
  }
}

// ---------------- host launcher ----------------
extern "C" void kernel_launch(void* const* d_in, const int* in_sizes, int n_in,
                              void* d_out, int out_size, void* d_ws, size_t ws_size,
                              hipStream_t stream) {
  const float* x = (const float*)d_in[0];
  const float* Wq = (const float*)d_in[1];
  const float* Wkv = (const float*)d_in[2];
  const float* Wo = (const float*)d_in[3];
  const float* bo = (const float*)d_in[4];
  const float* gamma = (const float*)d_in[5];
  const float* beta = (const float*)d_in[6];

  char* ws = (char*)d_ws;
  size_t o = 0;
  __bf16* x16 = (__bf16*)(ws + o);  o += (size_t)BATCH * SEQ * DIMC * 2;
  __bf16* wq16 = (__bf16*)(ws + o); o += (size_t)DIMC * DIMC * 2;
  __bf16* wkv16 = (__bf16*)(ws + o); o += (size_t)DIMC * DIMC * 2;
  __bf16* wo16 = (__bf16*)(ws + o); o += (size_t)DIMC * DIMC * 2;
  __bf16* kvn = (__bf16*)(ws + o);  o += (size_t)BATCH * HEADS * SEQ * DHH * 2;
  __bf16* kvnT = (__bf16*)(ws + o); o += (size_t)BATCH * HEADS * SEQ * DHH * 2;
  __bf16* qb = (__bf16*)(ws + o);   o += (size_t)BATCH * HEADS * LATENT * DHH * 2;
  __bf16* aout = (__bf16*)(ws + o); o += (size_t)BATCH * LATENT * DIMC * 2;

  k_convert<<<2048, 256, 0, stream>>>(x, x16, BATCH * SEQ * DIMC);
  k_convert3<<<1536, 256, 0, stream>>>(Wq, Wkv, Wo, wq16, wkv16, wo16);
  k_gemmqkv<<<dim3(8, 80), 256, 0, stream>>>(x16, wkv16, wq16, kvn, kvnT, qb, gamma, beta);
  k_flash5<<<1024, 256, 0, stream>>>(qb, kvn, kvnT, aout);
  k_gemm<0, 1><<<dim3(8, 16), 256, 0, stream>>>(aout, wo16, (float*)d_out, bo, 2048, 1024, 1024);
}